// Round 2
// baseline (811.864 us; speedup 1.0000x reference)
//
#include <hip/hip_runtime.h>
#include <cfloat>
#include <cmath>

#define B_ 4
#define S_ 1024
#define C_ 4096
#define K_ 64
#define D_ 256
#define NC 4160   // C_ + K_
#define TOPN 16
#define CAND 32   // pass-1 superset size per row

// ---------------- projection (fp64 accumulate): qp64[m][n] = sum_d q[m][d]*W[n][d] + b[n] ----------------
__global__ __launch_bounds__(256) void proj64_kernel(
    const float* __restrict__ q, const float* __restrict__ W,
    const float* __restrict__ bias, double* __restrict__ qp64)
{
  __shared__ alignas(16) float As[64][36];
  __shared__ alignas(16) float Ws[64][36];
  const int tid = threadIdx.x;
  const int m0 = blockIdx.x * 64;
  const int n0 = blockIdx.y * 64;
  const int tx = tid & 15;   // col group: cols n0 + tx + 16*j
  const int ty = tid >> 4;   // row group: rows m0 + ty*4 + i
  const int lr = tid >> 3;        // 0..31
  const int lk = (tid & 7) * 4;   // 0,4,...,28
  double acc[4][4] = {};
  for (int k0 = 0; k0 < D_; k0 += 32) {
    __syncthreads();
    {
      float4 a0 = *(const float4*)&q[(size_t)(m0 + lr) * D_ + k0 + lk];
      float4 a1 = *(const float4*)&q[(size_t)(m0 + lr + 32) * D_ + k0 + lk];
      *(float4*)&As[lr][lk] = a0;
      *(float4*)&As[lr + 32][lk] = a1;
      float4 w0 = *(const float4*)&W[(size_t)(n0 + lr) * D_ + k0 + lk];
      float4 w1 = *(const float4*)&W[(size_t)(n0 + lr + 32) * D_ + k0 + lk];
      *(float4*)&Ws[lr][lk] = w0;
      *(float4*)&Ws[lr + 32][lk] = w1;
    }
    __syncthreads();
    #pragma unroll
    for (int kk = 0; kk < 32; kk += 4) {
      float4 av[4], wv[4];
      #pragma unroll
      for (int i = 0; i < 4; ++i) av[i] = *(const float4*)&As[ty * 4 + i][kk];
      #pragma unroll
      for (int j = 0; j < 4; ++j) wv[j] = *(const float4*)&Ws[tx + 16 * j][kk];
      #pragma unroll
      for (int i = 0; i < 4; ++i)
        #pragma unroll
        for (int j = 0; j < 4; ++j) {
          acc[i][j] = fma((double)av[i].x, (double)wv[j].x, acc[i][j]);
          acc[i][j] = fma((double)av[i].y, (double)wv[j].y, acc[i][j]);
          acc[i][j] = fma((double)av[i].z, (double)wv[j].z, acc[i][j]);
          acc[i][j] = fma((double)av[i].w, (double)wv[j].w, acc[i][j]);
        }
    }
  }
  #pragma unroll
  for (int i = 0; i < 4; ++i) {
    const int m = m0 + ty * 4 + i;
    #pragma unroll
    for (int j = 0; j < 4; ++j) {
      const int n = n0 + tx + 16 * j;
      qp64[(size_t)m * D_ + n] = acc[i][j] + (double)bias[n];
    }
  }
}

// ---------------- qp row squared-norms (fp32, pass-1 guidance only) ----------------
__global__ __launch_bounds__(256) void qnorm_kernel(
    const double* __restrict__ qp64, float* __restrict__ qn)
{
  const int row = blockIdx.x * 4 + (threadIdx.x >> 6);
  const int lane = threadIdx.x & 63;
  const double* p = qp64 + (size_t)row * D_ + lane * 4;
  double2 a = *(const double2*)p;
  double2 b2 = *(const double2*)(p + 2);
  float s = (float)(a.x * a.x + a.y * a.y + b2.x * b2.x + b2.y * b2.y);
  #pragma unroll
  for (int off = 32; off > 0; off >>= 1) s += __shfl_down(s, off);
  if (lane == 0) qn[row] = s;
}

// ---------------- candidate row squared-norms (fp32) ----------------
__global__ __launch_bounds__(256) void norm_kernel(
    const float* __restrict__ x, float* __restrict__ outp,
    int rows_per_batch, int out_stride, int out_base)
{
  const int row = blockIdx.x * 4 + (threadIdx.x >> 6);
  const int lane = threadIdx.x & 63;
  const float4 v = *(const float4*)&x[(size_t)row * D_ + lane * 4];
  float s = v.x * v.x + v.y * v.y + v.z * v.z + v.w * v.w;
  #pragma unroll
  for (int off = 32; off > 0; off >>= 1) s += __shfl_down(s, off);
  if (lane == 0) {
    const int b = row / rows_per_batch;
    const int j = row - b * rows_per_batch;
    outp[(size_t)b * out_stride + out_base + j] = s;
  }
}

// ---------------- pass 1: fp32 distances + per-row top-32 candidate indices ----------------
__global__ __launch_bounds__(512) void dist_topk_kernel(
    const double* __restrict__ qp64, const float* __restrict__ ctx,
    const float* __restrict__ mem, const float* __restrict__ qn,
    const float* __restrict__ cn, int* __restrict__ topidx)
{
  const int b = blockIdx.x >> 6;
  const int rt = blockIdx.x & 63;
  const int row0 = rt * 16;
  const int tid = threadIdx.x;
  const int rg = tid & 15;
  const int cg = tid >> 4;   // 0..31

  __shared__ alignas(16) float qps[16][260];
  __shared__ alignas(16) float md[16][32][16];
  __shared__ alignas(16) int   mi[16][32][16];

  {  // stage 16 qp rows (convert fp64 -> fp32)
    const double* src = qp64 + ((size_t)b * S_ + row0) * D_;
    const int r = tid >> 5;            // 0..15
    const int kk = (tid & 31) * 8;     // 8 doubles each
    #pragma unroll
    for (int t = 0; t < 8; t += 2) {
      double2 v2 = *(const double2*)&src[(size_t)r * D_ + kk + t];
      qps[r][kk + t]     = (float)v2.x;
      qps[r][kk + t + 1] = (float)v2.y;
    }
  }
  const float myqn = qn[b * S_ + row0 + rg];
  __syncthreads();

  float ld[16]; int li[16];
  #pragma unroll
  for (int i = 0; i < TOPN; ++i) { ld[i] = FLT_MAX; li[i] = 0; }

  const float* cb_ptr = ctx + (size_t)b * C_ * D_;
  const float* cnb = cn + b * NC;

  for (int tile = 0; tile < 16; ++tile) {
    const int cb = tile * 256;
    const float* p = cb_ptr + (size_t)(cb + cg) * D_;
    float acc[8] = {};
    #pragma unroll 2
    for (int kq = 0; kq < D_; kq += 4) {
      const float4 qv = *(const float4*)&qps[rg][kq];
      #pragma unroll
      for (int j = 0; j < 8; ++j) {
        const float4 cv = *(const float4*)&p[(size_t)(32 * j) * D_ + kq];
        acc[j] = fmaf(qv.x, cv.x, acc[j]);
        acc[j] = fmaf(qv.y, cv.y, acc[j]);
        acc[j] = fmaf(qv.z, cv.z, acc[j]);
        acc[j] = fmaf(qv.w, cv.w, acc[j]);
      }
    }
    #pragma unroll
    for (int j = 0; j < 8; ++j) {
      const int c = cb + cg + 32 * j;
      const float d2 = myqn + cnb[c] - 2.0f * acc[j];
      if (d2 < ld[15]) {
        ld[15] = d2; li[15] = c;
        #pragma unroll
        for (int i = 15; i > 0; --i) {
          if (ld[i] < ld[i - 1]) {
            float td = ld[i]; ld[i] = ld[i - 1]; ld[i - 1] = td;
            int   ti = li[i]; li[i] = li[i - 1]; li[i - 1] = ti;
          }
        }
      }
    }
  }

  {  // memory candidates: 64 total, 2 per thread
    const float* p = mem + (size_t)b * K_ * D_ + (size_t)cg * D_;
    float acc[2] = {};
    #pragma unroll 2
    for (int kq = 0; kq < D_; kq += 4) {
      const float4 qv = *(const float4*)&qps[rg][kq];
      #pragma unroll
      for (int j = 0; j < 2; ++j) {
        const float4 cv = *(const float4*)&p[(size_t)(32 * j) * D_ + kq];
        acc[j] = fmaf(qv.x, cv.x, acc[j]);
        acc[j] = fmaf(qv.y, cv.y, acc[j]);
        acc[j] = fmaf(qv.z, cv.z, acc[j]);
        acc[j] = fmaf(qv.w, cv.w, acc[j]);
      }
    }
    #pragma unroll
    for (int j = 0; j < 2; ++j) {
      const int c = C_ + cg + 32 * j;
      const float d2 = myqn + cnb[c] - 2.0f * acc[j];
      if (d2 < ld[15]) {
        ld[15] = d2; li[15] = c;
        #pragma unroll
        for (int i = 15; i > 0; --i) {
          if (ld[i] < ld[i - 1]) {
            float td = ld[i]; ld[i] = ld[i - 1]; ld[i - 1] = td;
            int   ti = li[i]; li[i] = li[i - 1]; li[i - 1] = ti;
          }
        }
      }
    }
  }

  #pragma unroll
  for (int i = 0; i < TOPN; ++i) { md[rg][cg][i] = ld[i]; mi[rg][cg][i] = li[i]; }
  __syncthreads();
  if (tid < 16) {
    const int row = tid;
    float fd[CAND]; int fi[CAND];
    #pragma unroll
    for (int i = 0; i < CAND; ++i) { fd[i] = FLT_MAX; fi[i] = 0; }
    for (int g = 0; g < 32; ++g) {
      for (int i = 0; i < TOPN; ++i) {
        const float d2 = md[row][g][i];
        if (d2 >= fd[CAND - 1]) break;   // per-g list sorted ascending
        const int c = mi[row][g][i];
        fd[CAND - 1] = d2; fi[CAND - 1] = c;
        #pragma unroll
        for (int t = CAND - 1; t > 0; --t) {
          if (fd[t] < fd[t - 1]) {
            float td = fd[t]; fd[t] = fd[t - 1]; fd[t - 1] = td;
            int   ti = fi[t]; fi[t] = fi[t - 1]; fi[t - 1] = ti;
          }
        }
      }
    }
    int* dst = topidx + ((size_t)b * S_ + row0 + row) * CAND;
    #pragma unroll
    for (int i = 0; i < CAND; ++i) dst[i] = fi[i];
  }
}

// ---------------- pass 2: fp64 refine of 32 candidates -> top-16 ----------------
__global__ __launch_bounds__(256) void refine_kernel(
    const double* __restrict__ qp64, const float* __restrict__ ctx,
    const float* __restrict__ mem, const int* __restrict__ topidx,
    float* __restrict__ out)
{
  const int wv = threadIdx.x >> 6;               // wave in block (0..3)
  const int row_global = blockIdx.x * 4 + wv;    // 0..4095
  const int lane = threadIdx.x & 63;
  const int b = row_global >> 10;
  const int j = lane & 31;
  const int h = lane >> 5;

  __shared__ double d2s[4][32];
  __shared__ int    ids[4][32];

  const int ci = topidx[(size_t)row_global * CAND + j];
  const float* cp = (ci < C_) ? ctx + ((size_t)b * C_ + ci) * D_
                              : mem + ((size_t)b * K_ + (ci - C_)) * D_;
  const double* qrow = qp64 + (size_t)row_global * D_;

  double acc = 0.0;
  const int d0 = h * 128;
  #pragma unroll 4
  for (int d = 0; d < 128; d += 4) {
    float4 cv = *(const float4*)&cp[d0 + d];
    double df0 = qrow[d0 + d]     - (double)cv.x;
    double df1 = qrow[d0 + d + 1] - (double)cv.y;
    double df2 = qrow[d0 + d + 2] - (double)cv.z;
    double df3 = qrow[d0 + d + 3] - (double)cv.w;
    acc = fma(df0, df0, acc);
    acc = fma(df1, df1, acc);
    acc = fma(df2, df2, acc);
    acc = fma(df3, df3, acc);
  }
  acc += __shfl_down(acc, 32);
  if (lane < 32) { d2s[wv][j] = acc; ids[wv][j] = ci; }
  __syncthreads();

  if (lane == 0) {
    double fd[TOPN]; int fi[TOPN];
    #pragma unroll
    for (int i = 0; i < TOPN; ++i) { fd[i] = DBL_MAX; fi[i] = 0x7fffffff; }
    for (int k2 = 0; k2 < CAND; ++k2) {
      const double d2 = d2s[wv][k2];
      const int c = ids[wv][k2];
      if (d2 < fd[TOPN - 1] || (d2 == fd[TOPN - 1] && c < fi[TOPN - 1])) {
        fd[TOPN - 1] = d2; fi[TOPN - 1] = c;
        #pragma unroll
        for (int t = TOPN - 1; t > 0; --t) {
          if (fd[t] < fd[t - 1] || (fd[t] == fd[t - 1] && fi[t] < fi[t - 1])) {
            double td = fd[t]; fd[t] = fd[t - 1]; fd[t - 1] = td;
            int    ti = fi[t]; fi[t] = fi[t - 1]; fi[t - 1] = ti;
          }
        }
      }
    }
    const size_t obase = (size_t)row_global * TOPN;
    #pragma unroll
    for (int i = 0; i < TOPN; ++i) {
      out[obase + i] = (float)sqrt(fd[i] < 0.0 ? 0.0 : fd[i]);
      out[(size_t)B_ * S_ * TOPN + obase + i] = (float)fi[i];
    }
  }
}

extern "C" void kernel_launch(void* const* d_in, const int* in_sizes, int n_in,
                              void* d_out, int out_size, void* d_ws, size_t ws_size,
                              hipStream_t stream) {
  const float* q    = (const float*)d_in[0];
  const float* ctx  = (const float*)d_in[1];
  const float* mem  = (const float*)d_in[2];
  const float* W    = (const float*)d_in[3];
  const float* bias = (const float*)d_in[4];
  float* out = (float*)d_out;

  double* qp64 = (double*)d_ws;                          // 8 MB
  float*  qn   = (float*)(qp64 + (size_t)B_ * S_ * D_);  // 16 KB
  float*  cn   = qn + (size_t)B_ * S_;                   // 65 KB
  int* topidx  = (int*)(cn + (size_t)B_ * NC);           // 512 KB

  proj64_kernel<<<dim3(64, 4), 256, 0, stream>>>(q, W, bias, qp64);
  qnorm_kernel<<<(B_ * S_) / 4, 256, 0, stream>>>(qp64, qn);
  norm_kernel<<<(B_ * C_) / 4, 256, 0, stream>>>(ctx, cn, C_, NC, 0);
  norm_kernel<<<(B_ * K_) / 4, 256, 0, stream>>>(mem, cn, K_, NC, C_);
  dist_topk_kernel<<<256, 512, 0, stream>>>(qp64, ctx, mem, qn, cn, topidx);
  refine_kernel<<<(B_ * S_) / 4, 256, 0, stream>>>(qp64, ctx, mem, topidx, out);
}

// Round 3
// 348.584 us; speedup vs baseline: 2.3290x; 2.3290x over previous
//
#include <hip/hip_runtime.h>
#include <hip/hip_bf16.h>
#include <cfloat>
#include <cmath>

#define B_ 4
#define S_ 1024
#define C_ 4096
#define K_ 64
#define D_ 256
#define NC 4160   // C_ + K_
#define TOPN 16
#define CAND2 64  // 4 splits x 16 candidates fed to fp64 refine

typedef __attribute__((ext_vector_type(8))) short short8;
typedef __attribute__((ext_vector_type(4))) float f32x4;

// ---------------- projection (fp64 accumulate) + bf16 copy of qp ----------------
__global__ __launch_bounds__(256) void proj64_kernel(
    const float* __restrict__ q, const float* __restrict__ W,
    const float* __restrict__ bias, double* __restrict__ qp64,
    __hip_bfloat16* __restrict__ qpb)
{
  __shared__ alignas(16) float As[64][36];
  __shared__ alignas(16) float Ws[64][36];
  const int tid = threadIdx.x;
  const int m0 = blockIdx.x * 64;
  const int n0 = blockIdx.y * 64;
  const int tx = tid & 15;
  const int ty = tid >> 4;
  const int lr = tid >> 3;
  const int lk = (tid & 7) * 4;
  double acc[4][4] = {};
  for (int k0 = 0; k0 < D_; k0 += 32) {
    __syncthreads();
    {
      float4 a0 = *(const float4*)&q[(size_t)(m0 + lr) * D_ + k0 + lk];
      float4 a1 = *(const float4*)&q[(size_t)(m0 + lr + 32) * D_ + k0 + lk];
      *(float4*)&As[lr][lk] = a0;
      *(float4*)&As[lr + 32][lk] = a1;
      float4 w0 = *(const float4*)&W[(size_t)(n0 + lr) * D_ + k0 + lk];
      float4 w1 = *(const float4*)&W[(size_t)(n0 + lr + 32) * D_ + k0 + lk];
      *(float4*)&Ws[lr][lk] = w0;
      *(float4*)&Ws[lr + 32][lk] = w1;
    }
    __syncthreads();
    #pragma unroll
    for (int kk = 0; kk < 32; kk += 4) {
      float4 av[4], wv[4];
      #pragma unroll
      for (int i = 0; i < 4; ++i) av[i] = *(const float4*)&As[ty * 4 + i][kk];
      #pragma unroll
      for (int j = 0; j < 4; ++j) wv[j] = *(const float4*)&Ws[tx + 16 * j][kk];
      #pragma unroll
      for (int i = 0; i < 4; ++i)
        #pragma unroll
        for (int j = 0; j < 4; ++j) {
          acc[i][j] = fma((double)av[i].x, (double)wv[j].x, acc[i][j]);
          acc[i][j] = fma((double)av[i].y, (double)wv[j].y, acc[i][j]);
          acc[i][j] = fma((double)av[i].z, (double)wv[j].z, acc[i][j]);
          acc[i][j] = fma((double)av[i].w, (double)wv[j].w, acc[i][j]);
        }
    }
  }
  #pragma unroll
  for (int i = 0; i < 4; ++i) {
    const int m = m0 + ty * 4 + i;
    #pragma unroll
    for (int j = 0; j < 4; ++j) {
      const int n = n0 + tx + 16 * j;
      const double v = acc[i][j] + (double)bias[n];
      qp64[(size_t)m * D_ + n] = v;
      qpb[(size_t)m * D_ + n] = __float2bfloat16((float)v);
    }
  }
}

// ---------------- fp32 -> bf16 cast of candidates into [B][NC][D] layout ----------------
// src: [B][rows][D] fp32 (rows = C_ or K_); dst batch stride NC*D, base dst_base.
__global__ __launch_bounds__(256) void cvt_kernel(
    const float* __restrict__ src, __hip_bfloat16* __restrict__ dst,
    int log2_batch_f4, int dst_base)
{
  const int e4 = blockIdx.x * 256 + threadIdx.x;
  const int b = e4 >> log2_batch_f4;
  const int r4 = e4 & ((1 << log2_batch_f4) - 1);
  const float4 v = ((const float4*)src)[e4];
  __hip_bfloat16* d = dst + (size_t)b * (NC * D_) + dst_base + (size_t)r4 * 4;
  ushort4 o;
  __hip_bfloat16 h0 = __float2bfloat16(v.x); o.x = *(unsigned short*)&h0;
  __hip_bfloat16 h1 = __float2bfloat16(v.y); o.y = *(unsigned short*)&h1;
  __hip_bfloat16 h2 = __float2bfloat16(v.z); o.z = *(unsigned short*)&h2;
  __hip_bfloat16 h3 = __float2bfloat16(v.w); o.w = *(unsigned short*)&h3;
  *(ushort4*)d = o;
}

// ---------------- candidate row squared-norms (fp32) ----------------
__global__ __launch_bounds__(256) void norm_kernel(
    const float* __restrict__ x, float* __restrict__ outp,
    int rows_per_batch, int out_stride, int out_base)
{
  const int row = blockIdx.x * 4 + (threadIdx.x >> 6);
  const int lane = threadIdx.x & 63;
  const float4 v = *(const float4*)&x[(size_t)row * D_ + lane * 4];
  float s = v.x * v.x + v.y * v.y + v.z * v.z + v.w * v.w;
  #pragma unroll
  for (int off = 32; off > 0; off >>= 1) s += __shfl_down(s, off);
  if (lane == 0) {
    const int b = row / rows_per_batch;
    const int j = row - b * rows_per_batch;
    outp[(size_t)b * out_stride + out_base + j] = s;
  }
}

// ---------------- pass 1: bf16 MFMA scores + per-(row,split) top-16 indices ----------------
// grid 1024: blockIdx = b*256 + rt*4 + split. Block: 16 rows x 1/4 of candidates.
// score = cn[c] - 2*dot (monotone in d2 within a row).
#define LDW 132
__global__ __launch_bounds__(256) void dist_topk_kernel(
    const __hip_bfloat16* __restrict__ qpb, const __hip_bfloat16* __restrict__ candb,
    const float* __restrict__ cn, int* __restrict__ topidx)
{
  const int split = blockIdx.x & 3;
  const int rt = (blockIdx.x >> 2) & 63;
  const int b = blockIdx.x >> 8;
  const int row0 = rt * 16;
  const int tid = threadIdx.x;
  const int w = tid >> 6;          // wave 0..3
  const int lane = tid & 63;
  const int l15 = lane & 15;
  const int lg = lane >> 4;        // 0..3

  __shared__ float d2s[16][LDW];
  __shared__ float md[16][8][16];
  __shared__ int   mi[16][8][16];

  // A fragments (same 16 rows for all waves): row = row0+l15, k = s*32 + lg*8
  short8 afr[8];
  {
    const short* qrow = (const short*)qpb +
        ((size_t)(b * S_ + row0 + l15)) * D_ + lg * 8;
    #pragma unroll
    for (int s = 0; s < 8; ++s) afr[s] = *(const short8*)(qrow + s * 32);
  }

  const float* cnb = cn + b * NC;
  const short* cb_base = (const short*)candb + (size_t)b * NC * D_;

  float ld[16]; int li[16];
  #pragma unroll
  for (int i = 0; i < TOPN; ++i) { ld[i] = FLT_MAX; li[i] = 0; }

  const int rg = tid & 15;   // selection: row
  const int cg = tid >> 4;   // selection: col group 0..15

  const int ntiles = 8 + (split == 3 ? 1 : 0);
  for (int t = 0; t < ntiles; ++t) {
    const bool memtile = (t == 8);
    if (!memtile) {
      const int cb = (split * 8 + t) * 128;
      const short* p0 = cb_base + (size_t)(cb + w * 32 + l15) * D_ + lg * 8;
      const short* p1 = p0 + (size_t)16 * D_;
      f32x4 acc0 = {0.f, 0.f, 0.f, 0.f}, acc1 = {0.f, 0.f, 0.f, 0.f};
      #pragma unroll
      for (int s = 0; s < 8; ++s) {
        short8 b0 = *(const short8*)(p0 + s * 32);
        short8 b1 = *(const short8*)(p1 + s * 32);
        acc0 = __builtin_amdgcn_mfma_f32_16x16x32_bf16(afr[s], b0, acc0, 0, 0, 0);
        acc1 = __builtin_amdgcn_mfma_f32_16x16x32_bf16(afr[s], b1, acc1, 0, 0, 0);
      }
      const float cn0 = cnb[cb + w * 32 + l15];
      const float cn1 = cnb[cb + w * 32 + 16 + l15];
      #pragma unroll
      for (int r = 0; r < 4; ++r) {
        d2s[lg * 4 + r][w * 32 + l15]      = fmaf(-2.0f, acc0[r], cn0);
        d2s[lg * 4 + r][w * 32 + 16 + l15] = fmaf(-2.0f, acc1[r], cn1);
      }
    } else {  // 64 memory candidates, split 3 only
      const short* p0 = cb_base + (size_t)(C_ + w * 16 + l15) * D_ + lg * 8;
      f32x4 acc0 = {0.f, 0.f, 0.f, 0.f};
      #pragma unroll
      for (int s = 0; s < 8; ++s) {
        short8 b0 = *(const short8*)(p0 + s * 32);
        acc0 = __builtin_amdgcn_mfma_f32_16x16x32_bf16(afr[s], b0, acc0, 0, 0, 0);
      }
      const float cn0 = cnb[C_ + w * 16 + l15];
      #pragma unroll
      for (int r = 0; r < 4; ++r)
        d2s[lg * 4 + r][w * 16 + l15] = fmaf(-2.0f, acc0[r], cn0);
    }
    __syncthreads();
    {  // selection from the LDS score tile
      const int cb_sel = memtile ? C_ : (split * 8 + t) * 128;
      const int nj = memtile ? 4 : 8;
      for (int j = 0; j < nj; ++j) {
        const int cl = cg + 16 * j;
        const float d2 = d2s[rg][cl];
        if (d2 < ld[15]) {
          ld[15] = d2; li[15] = cb_sel + cl;
          #pragma unroll
          for (int i = 15; i > 0; --i) {
            if (ld[i] < ld[i - 1]) {
              float td = ld[i]; ld[i] = ld[i - 1]; ld[i - 1] = td;
              int   ti = li[i]; li[i] = li[i - 1]; li[i - 1] = ti;
            }
          }
        }
      }
    }
    __syncthreads();
  }

  // merge 16 per-thread lists per row -> per-(row,split) top-16; two rounds of 8
  float fd[16]; int fi[16];
  #pragma unroll
  for (int i = 0; i < TOPN; ++i) { fd[i] = FLT_MAX; fi[i] = 0; }
  for (int rnd = 0; rnd < 2; ++rnd) {
    if ((cg >> 3) == rnd) {
      #pragma unroll
      for (int i = 0; i < TOPN; ++i) {
        md[rg][cg & 7][i] = ld[i];
        mi[rg][cg & 7][i] = li[i];
      }
    }
    __syncthreads();
    if (tid < 16) {
      for (int g = 0; g < 8; ++g) {
        for (int i = 0; i < TOPN; ++i) {
          const float d2 = md[tid][g][i];
          if (d2 >= fd[15]) break;   // lists sorted ascending
          fd[15] = d2; fi[15] = mi[tid][g][i];
          #pragma unroll
          for (int s = 15; s > 0; --s) {
            if (fd[s] < fd[s - 1]) {
              float td = fd[s]; fd[s] = fd[s - 1]; fd[s - 1] = td;
              int   ti = fi[s]; fi[s] = fi[s - 1]; fi[s - 1] = ti;
            }
          }
        }
      }
    }
    __syncthreads();
  }
  if (tid < 16) {
    int* dst = topidx + ((size_t)(b * S_ + row0 + tid)) * CAND2 + split * TOPN;
    #pragma unroll
    for (int i = 0; i < TOPN; ++i) dst[i] = fi[i];
  }
}

// ---------------- pass 2: fp64 refine of 64 candidates -> top-16 ----------------
__global__ __launch_bounds__(256) void refine_kernel(
    const double* __restrict__ qp64, const float* __restrict__ ctx,
    const float* __restrict__ mem, const int* __restrict__ topidx,
    float* __restrict__ out)
{
  const int wv = threadIdx.x >> 6;
  const int row_global = blockIdx.x * 4 + wv;
  const int lane = threadIdx.x & 63;
  const int b = row_global >> 10;

  __shared__ double d2s[4][64];
  __shared__ int    ids[4][64];

  const int ci = topidx[(size_t)row_global * CAND2 + lane];
  const float* cp = (ci < C_) ? ctx + ((size_t)b * C_ + ci) * D_
                              : mem + ((size_t)b * K_ + (ci - C_)) * D_;
  const double* qrow = qp64 + (size_t)row_global * D_;

  double acc = 0.0;
  #pragma unroll 8
  for (int d = 0; d < D_; d += 4) {
    float4 cv = *(const float4*)&cp[d];
    double df0 = qrow[d]     - (double)cv.x;
    double df1 = qrow[d + 1] - (double)cv.y;
    double df2 = qrow[d + 2] - (double)cv.z;
    double df3 = qrow[d + 3] - (double)cv.w;
    acc = fma(df0, df0, acc);
    acc = fma(df1, df1, acc);
    acc = fma(df2, df2, acc);
    acc = fma(df3, df3, acc);
  }
  d2s[wv][lane] = acc;
  ids[wv][lane] = ci;
  __syncthreads();

  if (lane == 0) {
    double fd[TOPN]; int fi[TOPN];
    #pragma unroll
    for (int i = 0; i < TOPN; ++i) { fd[i] = DBL_MAX; fi[i] = 0x7fffffff; }
    for (int k2 = 0; k2 < CAND2; ++k2) {
      const double d2 = d2s[wv][k2];
      const int c = ids[wv][k2];
      if (d2 < fd[TOPN - 1] || (d2 == fd[TOPN - 1] && c < fi[TOPN - 1])) {
        fd[TOPN - 1] = d2; fi[TOPN - 1] = c;
        #pragma unroll
        for (int t = TOPN - 1; t > 0; --t) {
          if (fd[t] < fd[t - 1] || (fd[t] == fd[t - 1] && fi[t] < fi[t - 1])) {
            double td = fd[t]; fd[t] = fd[t - 1]; fd[t - 1] = td;
            int    ti = fi[t]; fi[t] = fi[t - 1]; fi[t - 1] = ti;
          }
        }
      }
    }
    const size_t obase = (size_t)row_global * TOPN;
    #pragma unroll
    for (int i = 0; i < TOPN; ++i) {
      out[obase + i] = (float)sqrt(fd[i] < 0.0 ? 0.0 : fd[i]);
      out[(size_t)B_ * S_ * TOPN + obase + i] = (float)fi[i];
    }
  }
}

extern "C" void kernel_launch(void* const* d_in, const int* in_sizes, int n_in,
                              void* d_out, int out_size, void* d_ws, size_t ws_size,
                              hipStream_t stream) {
  const float* q    = (const float*)d_in[0];
  const float* ctx  = (const float*)d_in[1];
  const float* mem  = (const float*)d_in[2];
  const float* W    = (const float*)d_in[3];
  const float* bias = (const float*)d_in[4];
  float* out = (float*)d_out;

  // workspace layout
  double* qp64 = (double*)d_ws;                                   // 8 MB
  __hip_bfloat16* qpb   = (__hip_bfloat16*)(qp64 + (size_t)B_ * S_ * D_);   // 2 MB
  __hip_bfloat16* candb = qpb + (size_t)B_ * S_ * D_;                       // 8.5 MB
  float* cn    = (float*)(candb + (size_t)B_ * NC * D_);          // 66.5 KB
  int*   topidx = (int*)(cn + (size_t)B_ * NC);                   // 1 MB

  proj64_kernel<<<dim3(64, 4), 256, 0, stream>>>(q, W, bias, qp64, qpb);
  // ctx cast: B*C*D/4 float4s, batch chunk C*D/4 = 2^18
  cvt_kernel<<<(B_ * C_ * D_ / 4) / 256, 256, 0, stream>>>(ctx, candb, 18, 0);
  // mem cast: batch chunk K*D/4 = 2^12
  cvt_kernel<<<(B_ * K_ * D_ / 4) / 256, 256, 0, stream>>>(mem, candb, 12, C_ * D_);
  norm_kernel<<<(B_ * C_) / 4, 256, 0, stream>>>(ctx, cn, C_, NC, 0);
  norm_kernel<<<(B_ * K_) / 4, 256, 0, stream>>>(mem, cn, K_, NC, C_);
  dist_topk_kernel<<<1024, 256, 0, stream>>>(qpb, candb, cn, topidx);
  refine_kernel<<<(B_ * S_) / 4, 256, 0, stream>>>(qp64, ctx, mem, topidx, out);
}

// Round 4
// 286.134 us; speedup vs baseline: 2.8374x; 1.2183x over previous
//
#include <hip/hip_runtime.h>
#include <hip/hip_bf16.h>
#include <cfloat>
#include <cmath>

#define B_ 4
#define S_ 1024
#define C_ 4096
#define K_ 64
#define D_ 256
#define NC 4160   // C_ + K_  (= 260 groups of 16)
#define TOPN 16
#define CAND2 64  // 4 splits x 16 candidates fed to fp64 refine

typedef __attribute__((ext_vector_type(8))) short short8;
typedef __attribute__((ext_vector_type(4))) float f32x4;

// ---------------- projection (fp64 accumulate) + bf16 copy of qp ----------------
__global__ __launch_bounds__(256) void proj64_kernel(
    const float* __restrict__ q, const float* __restrict__ W,
    const float* __restrict__ bias, double* __restrict__ qp64,
    __hip_bfloat16* __restrict__ qpb)
{
  __shared__ alignas(16) float As[64][36];
  __shared__ alignas(16) float Ws[64][36];
  const int tid = threadIdx.x;
  const int m0 = blockIdx.x * 64;
  const int n0 = blockIdx.y * 64;
  const int tx = tid & 15;
  const int ty = tid >> 4;
  const int lr = tid >> 3;
  const int lk = (tid & 7) * 4;
  double acc[4][4] = {};
  for (int k0 = 0; k0 < D_; k0 += 32) {
    __syncthreads();
    {
      float4 a0 = *(const float4*)&q[(size_t)(m0 + lr) * D_ + k0 + lk];
      float4 a1 = *(const float4*)&q[(size_t)(m0 + lr + 32) * D_ + k0 + lk];
      *(float4*)&As[lr][lk] = a0;
      *(float4*)&As[lr + 32][lk] = a1;
      float4 w0 = *(const float4*)&W[(size_t)(n0 + lr) * D_ + k0 + lk];
      float4 w1 = *(const float4*)&W[(size_t)(n0 + lr + 32) * D_ + k0 + lk];
      *(float4*)&Ws[lr][lk] = w0;
      *(float4*)&Ws[lr + 32][lk] = w1;
    }
    __syncthreads();
    #pragma unroll
    for (int kk = 0; kk < 32; kk += 4) {
      float4 av[4], wv[4];
      #pragma unroll
      for (int i = 0; i < 4; ++i) av[i] = *(const float4*)&As[ty * 4 + i][kk];
      #pragma unroll
      for (int j = 0; j < 4; ++j) wv[j] = *(const float4*)&Ws[tx + 16 * j][kk];
      #pragma unroll
      for (int i = 0; i < 4; ++i)
        #pragma unroll
        for (int j = 0; j < 4; ++j) {
          acc[i][j] = fma((double)av[i].x, (double)wv[j].x, acc[i][j]);
          acc[i][j] = fma((double)av[i].y, (double)wv[j].y, acc[i][j]);
          acc[i][j] = fma((double)av[i].z, (double)wv[j].z, acc[i][j]);
          acc[i][j] = fma((double)av[i].w, (double)wv[j].w, acc[i][j]);
        }
    }
  }
  #pragma unroll
  for (int i = 0; i < 4; ++i) {
    const int m = m0 + ty * 4 + i;
    #pragma unroll
    for (int j = 0; j < 4; ++j) {
      const int n = n0 + tx + 16 * j;
      const double v = acc[i][j] + (double)bias[n];
      qp64[(size_t)m * D_ + n] = v;
      qpb[(size_t)m * D_ + n] = __float2bfloat16((float)v);
    }
  }
}

// ---------------- fused fp32->bf16 cast + row squared-norms ----------------
// One wave covers exactly one row (64 float4 per row). src [B][rows][D] fp32.
__global__ __launch_bounds__(256) void cvt_norm_kernel(
    const float* __restrict__ src, __hip_bfloat16* __restrict__ dst,
    float* __restrict__ normp, int log2_rows_per_batch, int dst_base, int norm_base)
{
  const int e4 = blockIdx.x * 256 + threadIdx.x;   // float4 index
  const int row = e4 >> 6;
  const int b = row >> log2_rows_per_batch;
  const int r = row & ((1 << log2_rows_per_batch) - 1);
  const int k4 = e4 & 63;
  const float4 v = ((const float4*)src)[e4];
  __hip_bfloat16* d = dst + (size_t)b * (NC * D_) + dst_base + (size_t)r * D_ + k4 * 4;
  ushort4 o;
  __hip_bfloat16 h0 = __float2bfloat16(v.x); o.x = *(unsigned short*)&h0;
  __hip_bfloat16 h1 = __float2bfloat16(v.y); o.y = *(unsigned short*)&h1;
  __hip_bfloat16 h2 = __float2bfloat16(v.z); o.z = *(unsigned short*)&h2;
  __hip_bfloat16 h3 = __float2bfloat16(v.w); o.w = *(unsigned short*)&h3;
  *(ushort4*)d = o;
  float s = v.x * v.x + v.y * v.y + v.z * v.z + v.w * v.w;
  #pragma unroll
  for (int off = 32; off > 0; off >>= 1) s += __shfl_down(s, off);
  if ((threadIdx.x & 63) == 0) normp[b * NC + norm_base + r] = s;
}

// ---------------- pass 1: swapped-operand MFMA, in-register top-16 ----------------
// grid 1024: blockIdx = b*256 + rt*4 + split. 16 qp rows per block.
// mfma(A=cand, B=qp): lane gets 4 cands (regs) for qp row (lane&15).
// score = cn[c] - 2*dot (monotone in d2 within a row).
#define INSERT_CANDS(ACC, CBASE)                                              \
  {                                                                           \
    const float4 cn4 = *(const float4*)&cnb[(CBASE) + lg * 4];                \
    _Pragma("unroll")                                                         \
    for (int r = 0; r < 4; ++r) {                                             \
      const float d2 = fmaf(-2.0f, (ACC)[r], ((const float*)&cn4)[r]);        \
      if (d2 < ld[15]) {                                                      \
        ld[15] = d2; li[15] = (CBASE) + lg * 4 + r;                           \
        _Pragma("unroll")                                                     \
        for (int i = 15; i > 0; --i) {                                        \
          if (ld[i] < ld[i - 1]) {                                            \
            float td = ld[i]; ld[i] = ld[i - 1]; ld[i - 1] = td;              \
            int   ti = li[i]; li[i] = li[i - 1]; li[i - 1] = ti;              \
          }                                                                   \
        }                                                                     \
      }                                                                       \
    }                                                                         \
  }

__global__ __launch_bounds__(256) void dist_topk_kernel(
    const __hip_bfloat16* __restrict__ qpb, const __hip_bfloat16* __restrict__ candb,
    const float* __restrict__ cn, int* __restrict__ topidx)
{
  const int split = blockIdx.x & 3;
  const int rt = (blockIdx.x >> 2) & 63;
  const int b = blockIdx.x >> 8;
  const int row0 = rt * 16;
  const int tid = threadIdx.x;
  const int w = tid >> 6;          // wave 0..3
  const int lane = tid & 63;
  const int l15 = lane & 15;
  const int lg = lane >> 4;        // 0..3

  __shared__ float md[16][16][17];   // [lane-list id][row][i] (pad 17: conflict-free)
  __shared__ int   mi[16][16][17];

  // B fragments: the block's 16 qp rows. Lane holds qp row (row0+l15), k=lg*8+s*32.
  short8 bfr[8];
  {
    const short* qrow = (const short*)qpb + ((size_t)(b * S_ + row0 + l15)) * D_ + lg * 8;
    #pragma unroll
    for (int s = 0; s < 8; ++s) bfr[s] = *(const short8*)(qrow + s * 32);
  }

  const float* cnb = cn + b * NC;
  const short* cbp = (const short*)candb + (size_t)b * NC * D_ + lg * 8;

  float ld[16]; int li[16];
  #pragma unroll
  for (int i = 0; i < TOPN; ++i) { ld[i] = FLT_MAX; li[i] = 0; }

  // Candidate groups of 16: g = split + 4*gi, gi in {w, w+4, ..., w+60} (16 groups)
  // pair j: cA = 16*(split+4w) + 512*j, cB = cA + 256. Tail group (g = split+256,
  // the 64 memory cands) goes to wave 3.
  const int c0 = (split + 4 * w) * 16;
  const int ctail = split * 16 + C_;

  short8 aA[8], aB[8];
  #pragma unroll
  for (int s = 0; s < 8; ++s)
    aA[s] = *(const short8*)(cbp + (size_t)(c0 + l15) * D_ + s * 32);

  for (int j = 0; j < 8; ++j) {
    const int cA = c0 + 512 * j;
    const int cB = cA + 256;
    #pragma unroll
    for (int s = 0; s < 8; ++s)
      aB[s] = *(const short8*)(cbp + (size_t)(cB + l15) * D_ + s * 32);

    f32x4 acc = {0.f, 0.f, 0.f, 0.f};
    #pragma unroll
    for (int s = 0; s < 8; ++s)
      acc = __builtin_amdgcn_mfma_f32_16x16x32_bf16(aA[s], bfr[s], acc, 0, 0, 0);
    INSERT_CANDS(acc, cA);

    if (j < 7) {
      #pragma unroll
      for (int s = 0; s < 8; ++s)
        aA[s] = *(const short8*)(cbp + (size_t)(cA + 512 + l15) * D_ + s * 32);
    } else if (w == 3) {
      #pragma unroll
      for (int s = 0; s < 8; ++s)
        aA[s] = *(const short8*)(cbp + (size_t)(ctail + l15) * D_ + s * 32);
    }

    f32x4 acc2 = {0.f, 0.f, 0.f, 0.f};
    #pragma unroll
    for (int s = 0; s < 8; ++s)
      acc2 = __builtin_amdgcn_mfma_f32_16x16x32_bf16(aB[s], bfr[s], acc2, 0, 0, 0);
    INSERT_CANDS(acc2, cB);
  }
  if (w == 3) {   // memory-candidate group
    f32x4 acc = {0.f, 0.f, 0.f, 0.f};
    #pragma unroll
    for (int s = 0; s < 8; ++s)
      acc = __builtin_amdgcn_mfma_f32_16x16x32_bf16(aA[s], bfr[s], acc, 0, 0, 0);
    INSERT_CANDS(acc, ctail);
  }

  // dump per-lane lists; merge 16 lists per row
  const int lid = w * 4 + lg;
  #pragma unroll
  for (int i = 0; i < TOPN; ++i) { md[lid][l15][i] = ld[i]; mi[lid][l15][i] = li[i]; }
  __syncthreads();

  if (tid < 16) {
    const int row = tid;
    float fd[16]; int fi[16];
    #pragma unroll
    for (int i = 0; i < TOPN; ++i) { fd[i] = FLT_MAX; fi[i] = 0; }
    for (int g = 0; g < 16; ++g) {
      for (int i = 0; i < TOPN; ++i) {
        const float d2 = md[g][row][i];
        if (d2 >= fd[15]) break;   // per-g list sorted ascending
        fd[15] = d2; fi[15] = mi[g][row][i];
        #pragma unroll
        for (int s = 15; s > 0; --s) {
          if (fd[s] < fd[s - 1]) {
            float td = fd[s]; fd[s] = fd[s - 1]; fd[s - 1] = td;
            int   ti = fi[s]; fi[s] = fi[s - 1]; fi[s - 1] = ti;
          }
        }
      }
    }
    int* dst = topidx + ((size_t)(b * S_ + row0 + row)) * CAND2 + split * TOPN;
    #pragma unroll
    for (int i = 0; i < TOPN; ++i) dst[i] = fi[i];
  }
}

// ---------------- pass 2: fp64 refine of 64 candidates -> top-16 ----------------
__global__ __launch_bounds__(256) void refine_kernel(
    const double* __restrict__ qp64, const float* __restrict__ ctx,
    const float* __restrict__ mem, const int* __restrict__ topidx,
    float* __restrict__ out)
{
  const int wv = threadIdx.x >> 6;
  const int row_global = blockIdx.x * 4 + wv;
  const int lane = threadIdx.x & 63;
  const int b = row_global >> 10;

  __shared__ double d2s[4][64];
  __shared__ int    ids[4][64];

  const int ci = topidx[(size_t)row_global * CAND2 + lane];
  const float* cp = (ci < C_) ? ctx + ((size_t)b * C_ + ci) * D_
                              : mem + ((size_t)b * K_ + (ci - C_)) * D_;
  const double* qrow = qp64 + (size_t)row_global * D_;

  double acc = 0.0;
  #pragma unroll 8
  for (int d = 0; d < D_; d += 4) {
    float4 cv = *(const float4*)&cp[d];
    double df0 = qrow[d]     - (double)cv.x;
    double df1 = qrow[d + 1] - (double)cv.y;
    double df2 = qrow[d + 2] - (double)cv.z;
    double df3 = qrow[d + 3] - (double)cv.w;
    acc = fma(df0, df0, acc);
    acc = fma(df1, df1, acc);
    acc = fma(df2, df2, acc);
    acc = fma(df3, df3, acc);
  }
  d2s[wv][lane] = acc;
  ids[wv][lane] = ci;
  __syncthreads();

  if (lane == 0) {
    double fd[TOPN]; int fi[TOPN];
    #pragma unroll
    for (int i = 0; i < TOPN; ++i) { fd[i] = DBL_MAX; fi[i] = 0x7fffffff; }
    for (int k2 = 0; k2 < CAND2; ++k2) {
      const double d2 = d2s[wv][k2];
      const int c = ids[wv][k2];
      if (d2 < fd[TOPN - 1] || (d2 == fd[TOPN - 1] && c < fi[TOPN - 1])) {
        fd[TOPN - 1] = d2; fi[TOPN - 1] = c;
        #pragma unroll
        for (int t = TOPN - 1; t > 0; --t) {
          if (fd[t] < fd[t - 1] || (fd[t] == fd[t - 1] && fi[t] < fi[t - 1])) {
            double td = fd[t]; fd[t] = fd[t - 1]; fd[t - 1] = td;
            int    ti = fi[t]; fi[t] = fi[t - 1]; fi[t - 1] = ti;
          }
        }
      }
    }
    const size_t obase = (size_t)row_global * TOPN;
    #pragma unroll
    for (int i = 0; i < TOPN; ++i) {
      out[obase + i] = (float)sqrt(fd[i] < 0.0 ? 0.0 : fd[i]);
      out[(size_t)B_ * S_ * TOPN + obase + i] = (float)fi[i];
    }
  }
}

extern "C" void kernel_launch(void* const* d_in, const int* in_sizes, int n_in,
                              void* d_out, int out_size, void* d_ws, size_t ws_size,
                              hipStream_t stream) {
  const float* q    = (const float*)d_in[0];
  const float* ctx  = (const float*)d_in[1];
  const float* mem  = (const float*)d_in[2];
  const float* W    = (const float*)d_in[3];
  const float* bias = (const float*)d_in[4];
  float* out = (float*)d_out;

  // workspace layout
  double* qp64 = (double*)d_ws;                                             // 8 MB
  __hip_bfloat16* qpb   = (__hip_bfloat16*)(qp64 + (size_t)B_ * S_ * D_);   // 2 MB
  __hip_bfloat16* candb = qpb + (size_t)B_ * S_ * D_;                       // 8.5 MB
  float* cn    = (float*)(candb + (size_t)B_ * NC * D_);                    // 66.5 KB
  int*   topidx = (int*)(cn + (size_t)B_ * NC);                             // 1 MB

  proj64_kernel<<<dim3(64, 4), 256, 0, stream>>>(q, W, bias, qp64, qpb);
  // ctx: rows/batch = 4096 (log2 12), grid = B*C*64/256 = 4096 blocks
  cvt_norm_kernel<<<(B_ * C_ * 64) / 256, 256, 0, stream>>>(ctx, candb, cn, 12, 0, 0);
  // mem: rows/batch = 64 (log2 6), grid = B*K*64/256 = 64 blocks
  cvt_norm_kernel<<<(B_ * K_ * 64) / 256, 256, 0, stream>>>(mem, candb, cn, 6, C_ * D_, C_);
  dist_topk_kernel<<<1024, 256, 0, stream>>>(qpb, candb, cn, topidx);
  refine_kernel<<<(B_ * S_) / 4, 256, 0, stream>>>(qp64, ctx, mem, topidx, out);
}

// Round 5
// 255.036 us; speedup vs baseline: 3.1833x; 1.1219x over previous
//
#include <hip/hip_runtime.h>
#include <hip/hip_bf16.h>
#include <cfloat>
#include <cmath>

#define B_ 4
#define S_ 1024
#define C_ 4096
#define K_ 64
#define D_ 256
#define NC 4160   // C_ + K_  (= 260 groups of 16)
#define TOPN 16
#define CAND2 64  // 4 splits x 16 candidates fed to fp64 refine

typedef __attribute__((ext_vector_type(8))) short short8;
typedef __attribute__((ext_vector_type(4))) float f32x4;

// ---------------- projection (fp64 accumulate) + bf16 copy of qp ----------------
__global__ __launch_bounds__(256) void proj64_kernel(
    const float* __restrict__ q, const float* __restrict__ W,
    const float* __restrict__ bias, double* __restrict__ qp64,
    __hip_bfloat16* __restrict__ qpb)
{
  __shared__ alignas(16) float As[64][36];
  __shared__ alignas(16) float Ws[64][36];
  const int tid = threadIdx.x;
  const int m0 = blockIdx.x * 64;
  const int n0 = blockIdx.y * 64;
  const int tx = tid & 15;
  const int ty = tid >> 4;
  const int lr = tid >> 3;
  const int lk = (tid & 7) * 4;
  double acc[4][4] = {};
  for (int k0 = 0; k0 < D_; k0 += 32) {
    __syncthreads();
    {
      float4 a0 = *(const float4*)&q[(size_t)(m0 + lr) * D_ + k0 + lk];
      float4 a1 = *(const float4*)&q[(size_t)(m0 + lr + 32) * D_ + k0 + lk];
      *(float4*)&As[lr][lk] = a0;
      *(float4*)&As[lr + 32][lk] = a1;
      float4 w0 = *(const float4*)&W[(size_t)(n0 + lr) * D_ + k0 + lk];
      float4 w1 = *(const float4*)&W[(size_t)(n0 + lr + 32) * D_ + k0 + lk];
      *(float4*)&Ws[lr][lk] = w0;
      *(float4*)&Ws[lr + 32][lk] = w1;
    }
    __syncthreads();
    #pragma unroll
    for (int kk = 0; kk < 32; kk += 4) {
      float4 av[4], wv[4];
      #pragma unroll
      for (int i = 0; i < 4; ++i) av[i] = *(const float4*)&As[ty * 4 + i][kk];
      #pragma unroll
      for (int j = 0; j < 4; ++j) wv[j] = *(const float4*)&Ws[tx + 16 * j][kk];
      #pragma unroll
      for (int i = 0; i < 4; ++i)
        #pragma unroll
        for (int j = 0; j < 4; ++j) {
          acc[i][j] = fma((double)av[i].x, (double)wv[j].x, acc[i][j]);
          acc[i][j] = fma((double)av[i].y, (double)wv[j].y, acc[i][j]);
          acc[i][j] = fma((double)av[i].z, (double)wv[j].z, acc[i][j]);
          acc[i][j] = fma((double)av[i].w, (double)wv[j].w, acc[i][j]);
        }
    }
  }
  #pragma unroll
  for (int i = 0; i < 4; ++i) {
    const int m = m0 + ty * 4 + i;
    #pragma unroll
    for (int j = 0; j < 4; ++j) {
      const int n = n0 + tx + 16 * j;
      const double v = acc[i][j] + (double)bias[n];
      qp64[(size_t)m * D_ + n] = v;
      qpb[(size_t)m * D_ + n] = __float2bfloat16((float)v);
    }
  }
}

// ---------------- fused fp32->bf16 cast + row squared-norms ----------------
__global__ __launch_bounds__(256) void cvt_norm_kernel(
    const float* __restrict__ src, __hip_bfloat16* __restrict__ dst,
    float* __restrict__ normp, int log2_rows_per_batch, int dst_base, int norm_base)
{
  const int e4 = blockIdx.x * 256 + threadIdx.x;   // float4 index
  const int row = e4 >> 6;
  const int b = row >> log2_rows_per_batch;
  const int r = row & ((1 << log2_rows_per_batch) - 1);
  const int k4 = e4 & 63;
  const float4 v = ((const float4*)src)[e4];
  __hip_bfloat16* d = dst + (size_t)b * (NC * D_) + dst_base + (size_t)r * D_ + k4 * 4;
  ushort4 o;
  __hip_bfloat16 h0 = __float2bfloat16(v.x); o.x = *(unsigned short*)&h0;
  __hip_bfloat16 h1 = __float2bfloat16(v.y); o.y = *(unsigned short*)&h1;
  __hip_bfloat16 h2 = __float2bfloat16(v.z); o.z = *(unsigned short*)&h2;
  __hip_bfloat16 h3 = __float2bfloat16(v.w); o.w = *(unsigned short*)&h3;
  *(ushort4*)d = o;
  float s = v.x * v.x + v.y * v.y + v.z * v.z + v.w * v.w;
  #pragma unroll
  for (int off = 32; off > 0; off >>= 1) s += __shfl_down(s, off);
  if ((threadIdx.x & 63) == 0) normp[b * NC + norm_base + r] = s;
}

// ---------------- pass 1: swapped-operand MFMA, in-register top-16 ----------------
#define INSERT_CANDS(ACC, CBASE)                                              \
  {                                                                           \
    const float4 cn4 = *(const float4*)&cnb[(CBASE) + lg * 4];                \
    _Pragma("unroll")                                                         \
    for (int r = 0; r < 4; ++r) {                                             \
      const float d2 = fmaf(-2.0f, (ACC)[r], ((const float*)&cn4)[r]);        \
      if (d2 < ld[15]) {                                                      \
        ld[15] = d2; li[15] = (CBASE) + lg * 4 + r;                           \
        _Pragma("unroll")                                                     \
        for (int i = 15; i > 0; --i) {                                        \
          if (ld[i] < ld[i - 1]) {                                            \
            float td = ld[i]; ld[i] = ld[i - 1]; ld[i - 1] = td;              \
            int   ti = li[i]; li[i] = li[i - 1]; li[i - 1] = ti;              \
          }                                                                   \
        }                                                                     \
      }                                                                       \
    }                                                                         \
  }

__global__ __launch_bounds__(256) void dist_topk_kernel(
    const __hip_bfloat16* __restrict__ qpb, const __hip_bfloat16* __restrict__ candb,
    const float* __restrict__ cn, int* __restrict__ topidx)
{
  const int split = blockIdx.x & 3;
  const int rt = (blockIdx.x >> 2) & 63;
  const int b = blockIdx.x >> 8;
  const int row0 = rt * 16;
  const int tid = threadIdx.x;
  const int w = tid >> 6;          // wave 0..3
  const int lane = tid & 63;
  const int l15 = lane & 15;
  const int lg = lane >> 4;        // 0..3

  __shared__ float md[16][16][17];
  __shared__ int   mi[16][16][17];

  short8 bfr[8];
  {
    const short* qrow = (const short*)qpb + ((size_t)(b * S_ + row0 + l15)) * D_ + lg * 8;
    #pragma unroll
    for (int s = 0; s < 8; ++s) bfr[s] = *(const short8*)(qrow + s * 32);
  }

  const float* cnb = cn + b * NC;
  const short* cbp = (const short*)candb + (size_t)b * NC * D_ + lg * 8;

  float ld[16]; int li[16];
  #pragma unroll
  for (int i = 0; i < TOPN; ++i) { ld[i] = FLT_MAX; li[i] = 0; }

  const int c0 = (split + 4 * w) * 16;
  const int ctail = split * 16 + C_;

  short8 aA[8], aB[8];
  #pragma unroll
  for (int s = 0; s < 8; ++s)
    aA[s] = *(const short8*)(cbp + (size_t)(c0 + l15) * D_ + s * 32);

  for (int j = 0; j < 8; ++j) {
    const int cA = c0 + 512 * j;
    const int cB = cA + 256;
    #pragma unroll
    for (int s = 0; s < 8; ++s)
      aB[s] = *(const short8*)(cbp + (size_t)(cB + l15) * D_ + s * 32);

    f32x4 acc = {0.f, 0.f, 0.f, 0.f};
    #pragma unroll
    for (int s = 0; s < 8; ++s)
      acc = __builtin_amdgcn_mfma_f32_16x16x32_bf16(aA[s], bfr[s], acc, 0, 0, 0);
    INSERT_CANDS(acc, cA);

    if (j < 7) {
      #pragma unroll
      for (int s = 0; s < 8; ++s)
        aA[s] = *(const short8*)(cbp + (size_t)(cA + 512 + l15) * D_ + s * 32);
    } else if (w == 3) {
      #pragma unroll
      for (int s = 0; s < 8; ++s)
        aA[s] = *(const short8*)(cbp + (size_t)(ctail + l15) * D_ + s * 32);
    }

    f32x4 acc2 = {0.f, 0.f, 0.f, 0.f};
    #pragma unroll
    for (int s = 0; s < 8; ++s)
      acc2 = __builtin_amdgcn_mfma_f32_16x16x32_bf16(aB[s], bfr[s], acc2, 0, 0, 0);
    INSERT_CANDS(acc2, cB);
  }
  if (w == 3) {
    f32x4 acc = {0.f, 0.f, 0.f, 0.f};
    #pragma unroll
    for (int s = 0; s < 8; ++s)
      acc = __builtin_amdgcn_mfma_f32_16x16x32_bf16(aA[s], bfr[s], acc, 0, 0, 0);
    INSERT_CANDS(acc, ctail);
  }

  const int lid = w * 4 + lg;
  #pragma unroll
  for (int i = 0; i < TOPN; ++i) { md[lid][l15][i] = ld[i]; mi[lid][l15][i] = li[i]; }
  __syncthreads();

  if (tid < 16) {
    const int row = tid;
    float fd[16]; int fi[16];
    #pragma unroll
    for (int i = 0; i < TOPN; ++i) { fd[i] = FLT_MAX; fi[i] = 0; }
    for (int g = 0; g < 16; ++g) {
      for (int i = 0; i < TOPN; ++i) {
        const float d2 = md[g][row][i];
        if (d2 >= fd[15]) break;
        fd[15] = d2; fi[15] = mi[g][row][i];
        #pragma unroll
        for (int s = 15; s > 0; --s) {
          if (fd[s] < fd[s - 1]) {
            float td = fd[s]; fd[s] = fd[s - 1]; fd[s - 1] = td;
            int   ti = fi[s]; fi[s] = fi[s - 1]; fi[s - 1] = ti;
          }
        }
      }
    }
    int* dst = topidx + ((size_t)(b * S_ + row0 + row)) * CAND2 + split * TOPN;
    #pragma unroll
    for (int i = 0; i < TOPN; ++i) dst[i] = fi[i];
  }
}

// ---------------- pass 2: fp64 refine, coalesced: 1 row/block, cand-pair/wave-iter ----------------
__global__ __launch_bounds__(256) void refine_kernel(
    const double* __restrict__ qp64, const float* __restrict__ ctx,
    const float* __restrict__ mem, const int* __restrict__ topidx,
    float* __restrict__ out)
{
  const int row_global = blockIdx.x;
  const int tid = threadIdx.x;
  const int w = tid >> 6;         // wave 0..3: candidates [w*16, w*16+16)
  const int lane = tid & 63;
  const int c2 = lane >> 5;       // which cand of the pair
  const int ll = lane & 31;       // dim slice: [ll*8, ll*8+8)
  const int b = row_global >> 10;

  __shared__ double d2s[64];
  __shared__ int    ids_s[64];

  // qrow slice (coalesced, reused for all 16 candidates of this wave)
  const double* qrow = qp64 + (size_t)row_global * D_;
  double qd[8];
  #pragma unroll
  for (int t = 0; t < 8; t += 2) {
    double2 v = *(const double2*)&qrow[ll * 8 + t];
    qd[t] = v.x; qd[t + 1] = v.y;
  }

  const int* tix = topidx + (size_t)row_global * CAND2 + w * 16;
  #pragma unroll 2
  for (int j = 0; j < 8; ++j) {
    const int p = 2 * j + c2;
    const int ci = tix[p];
    const float* cp = (ci < C_) ? ctx + ((size_t)b * C_ + ci) * D_
                                : mem + ((size_t)b * K_ + (ci - C_)) * D_;
    const float4 cv0 = *(const float4*)&cp[ll * 8];
    const float4 cv1 = *(const float4*)&cp[ll * 8 + 4];
    double a0 = 0.0, a1 = 0.0, df;
    df = qd[0] - (double)cv0.x; a0 = fma(df, df, a0);
    df = qd[1] - (double)cv0.y; a1 = fma(df, df, a1);
    df = qd[2] - (double)cv0.z; a0 = fma(df, df, a0);
    df = qd[3] - (double)cv0.w; a1 = fma(df, df, a1);
    df = qd[4] - (double)cv1.x; a0 = fma(df, df, a0);
    df = qd[5] - (double)cv1.y; a1 = fma(df, df, a1);
    df = qd[6] - (double)cv1.z; a0 = fma(df, df, a0);
    df = qd[7] - (double)cv1.w; a1 = fma(df, df, a1);
    double acc = a0 + a1;
    #pragma unroll
    for (int off = 16; off > 0; off >>= 1) acc += __shfl_down(acc, off, 32);
    if (ll == 0) { d2s[w * 16 + p] = acc; ids_s[w * 16 + p] = ci; }
  }
  __syncthreads();

  if (tid == 0) {
    double fd[TOPN]; int fi[TOPN];
    #pragma unroll
    for (int i = 0; i < TOPN; ++i) { fd[i] = DBL_MAX; fi[i] = 0x7fffffff; }
    for (int k2 = 0; k2 < CAND2; ++k2) {
      const double d2 = d2s[k2];
      const int c = ids_s[k2];
      if (d2 < fd[TOPN - 1] || (d2 == fd[TOPN - 1] && c < fi[TOPN - 1])) {
        fd[TOPN - 1] = d2; fi[TOPN - 1] = c;
        #pragma unroll
        for (int t = TOPN - 1; t > 0; --t) {
          if (fd[t] < fd[t - 1] || (fd[t] == fd[t - 1] && fi[t] < fi[t - 1])) {
            double td = fd[t]; fd[t] = fd[t - 1]; fd[t - 1] = td;
            int    ti = fi[t]; fi[t] = fi[t - 1]; fi[t - 1] = ti;
          }
        }
      }
    }
    const size_t obase = (size_t)row_global * TOPN;
    #pragma unroll
    for (int i = 0; i < TOPN; ++i) {
      out[obase + i] = (float)sqrt(fd[i] < 0.0 ? 0.0 : fd[i]);
      out[(size_t)B_ * S_ * TOPN + obase + i] = (float)fi[i];
    }
  }
}

extern "C" void kernel_launch(void* const* d_in, const int* in_sizes, int n_in,
                              void* d_out, int out_size, void* d_ws, size_t ws_size,
                              hipStream_t stream) {
  const float* q    = (const float*)d_in[0];
  const float* ctx  = (const float*)d_in[1];
  const float* mem  = (const float*)d_in[2];
  const float* W    = (const float*)d_in[3];
  const float* bias = (const float*)d_in[4];
  float* out = (float*)d_out;

  double* qp64 = (double*)d_ws;                                             // 8 MB
  __hip_bfloat16* qpb   = (__hip_bfloat16*)(qp64 + (size_t)B_ * S_ * D_);   // 2 MB
  __hip_bfloat16* candb = qpb + (size_t)B_ * S_ * D_;                       // 8.5 MB
  float* cn    = (float*)(candb + (size_t)B_ * NC * D_);                    // 66.5 KB
  int*   topidx = (int*)(cn + (size_t)B_ * NC);                             // 1 MB

  proj64_kernel<<<dim3(64, 4), 256, 0, stream>>>(q, W, bias, qp64, qpb);
  cvt_norm_kernel<<<(B_ * C_ * 64) / 256, 256, 0, stream>>>(ctx, candb, cn, 12, 0, 0);
  cvt_norm_kernel<<<(B_ * K_ * 64) / 256, 256, 0, stream>>>(mem, candb, cn, 6, C_ * D_, C_);
  dist_topk_kernel<<<1024, 256, 0, stream>>>(qpb, candb, cn, topidx);
  refine_kernel<<<B_ * S_, 256, 0, stream>>>(qp64, ctx, mem, topidx, out);
}

// Round 6
// 252.516 us; speedup vs baseline: 3.2151x; 1.0100x over previous
//
#include <hip/hip_runtime.h>
#include <hip/hip_bf16.h>
#include <cfloat>
#include <cmath>

#define B_ 4
#define S_ 1024
#define C_ 4096
#define K_ 64
#define D_ 256
#define NC 4160   // C_ + K_  (= 260 groups of 16)
#define TOPN 16
#define CAND2 64  // 4 splits x 16 candidates fed to fp64 refine

typedef __attribute__((ext_vector_type(8))) short short8;
typedef __attribute__((ext_vector_type(4))) float f32x4;

// ---------------- projection (fp64 accumulate) + bf16 copy of qp ----------------
__global__ __launch_bounds__(256) void proj64_kernel(
    const float* __restrict__ q, const float* __restrict__ W,
    const float* __restrict__ bias, double* __restrict__ qp64,
    __hip_bfloat16* __restrict__ qpb)
{
  __shared__ alignas(16) float As[64][36];
  __shared__ alignas(16) float Ws[64][36];
  const int tid = threadIdx.x;
  const int m0 = blockIdx.x * 64;
  const int n0 = blockIdx.y * 64;
  const int tx = tid & 15;
  const int ty = tid >> 4;
  const int lr = tid >> 3;
  const int lk = (tid & 7) * 4;
  double acc[4][4] = {};
  for (int k0 = 0; k0 < D_; k0 += 32) {
    __syncthreads();
    {
      float4 a0 = *(const float4*)&q[(size_t)(m0 + lr) * D_ + k0 + lk];
      float4 a1 = *(const float4*)&q[(size_t)(m0 + lr + 32) * D_ + k0 + lk];
      *(float4*)&As[lr][lk] = a0;
      *(float4*)&As[lr + 32][lk] = a1;
      float4 w0 = *(const float4*)&W[(size_t)(n0 + lr) * D_ + k0 + lk];
      float4 w1 = *(const float4*)&W[(size_t)(n0 + lr + 32) * D_ + k0 + lk];
      *(float4*)&Ws[lr][lk] = w0;
      *(float4*)&Ws[lr + 32][lk] = w1;
    }
    __syncthreads();
    #pragma unroll
    for (int kk = 0; kk < 32; kk += 4) {
      float4 av[4], wv[4];
      #pragma unroll
      for (int i = 0; i < 4; ++i) av[i] = *(const float4*)&As[ty * 4 + i][kk];
      #pragma unroll
      for (int j = 0; j < 4; ++j) wv[j] = *(const float4*)&Ws[tx + 16 * j][kk];
      #pragma unroll
      for (int i = 0; i < 4; ++i)
        #pragma unroll
        for (int j = 0; j < 4; ++j) {
          acc[i][j] = fma((double)av[i].x, (double)wv[j].x, acc[i][j]);
          acc[i][j] = fma((double)av[i].y, (double)wv[j].y, acc[i][j]);
          acc[i][j] = fma((double)av[i].z, (double)wv[j].z, acc[i][j]);
          acc[i][j] = fma((double)av[i].w, (double)wv[j].w, acc[i][j]);
        }
    }
  }
  #pragma unroll
  for (int i = 0; i < 4; ++i) {
    const int m = m0 + ty * 4 + i;
    #pragma unroll
    for (int j = 0; j < 4; ++j) {
      const int n = n0 + tx + 16 * j;
      const double v = acc[i][j] + (double)bias[n];
      qp64[(size_t)m * D_ + n] = v;
      qpb[(size_t)m * D_ + n] = __float2bfloat16((float)v);
    }
  }
}

// ---------------- fused fp32->bf16 cast + row squared-norms ----------------
__global__ __launch_bounds__(256) void cvt_norm_kernel(
    const float* __restrict__ src, __hip_bfloat16* __restrict__ dst,
    float* __restrict__ normp, int log2_rows_per_batch, int dst_base, int norm_base)
{
  const int e4 = blockIdx.x * 256 + threadIdx.x;   // float4 index
  const int row = e4 >> 6;
  const int b = row >> log2_rows_per_batch;
  const int r = row & ((1 << log2_rows_per_batch) - 1);
  const int k4 = e4 & 63;
  const float4 v = ((const float4*)src)[e4];
  __hip_bfloat16* d = dst + (size_t)b * (NC * D_) + dst_base + (size_t)r * D_ + k4 * 4;
  ushort4 o;
  __hip_bfloat16 h0 = __float2bfloat16(v.x); o.x = *(unsigned short*)&h0;
  __hip_bfloat16 h1 = __float2bfloat16(v.y); o.y = *(unsigned short*)&h1;
  __hip_bfloat16 h2 = __float2bfloat16(v.z); o.z = *(unsigned short*)&h2;
  __hip_bfloat16 h3 = __float2bfloat16(v.w); o.w = *(unsigned short*)&h3;
  *(ushort4*)d = o;
  float s = v.x * v.x + v.y * v.y + v.z * v.z + v.w * v.w;
  #pragma unroll
  for (int off = 32; off > 0; off >>= 1) s += __shfl_down(s, off);
  if ((threadIdx.x & 63) == 0) normp[b * NC + norm_base + r] = s;
}

// ---------------- pass 1: swapped-operand MFMA, packed-key in-register top-16 ----------------
// key = (float_bits(d2) & ~0x1FFF) | candidate_index  (d2 > 0 always here, so
// u32 order == d2 order up to 1-ulp-of-2^-10 truncation; selection-only error,
// refine recomputes exact fp64). Insert = single u32 sorted-insert.
#define INSERT_CANDS(ACC, CBASE)                                              \
  {                                                                           \
    const float4 cn4 = *(const float4*)&cnb[(CBASE) + lg * 4];                \
    _Pragma("unroll")                                                         \
    for (int r = 0; r < 4; ++r) {                                             \
      const float d2 = fmaf(-2.0f, (ACC)[r], ((const float*)&cn4)[r]);        \
      const unsigned key = (__float_as_uint(d2) & 0xFFFFE000u)                \
                           | (unsigned)((CBASE) + lg * 4 + r);                \
      if (key < ld[15]) {                                                     \
        ld[15] = key;                                                         \
        _Pragma("unroll")                                                     \
        for (int i = 15; i > 0; --i) {                                        \
          if (ld[i] < ld[i - 1]) {                                            \
            unsigned t = ld[i]; ld[i] = ld[i - 1]; ld[i - 1] = t;             \
          }                                                                   \
        }                                                                     \
      }                                                                       \
    }                                                                         \
  }

__global__ __launch_bounds__(256) void dist_topk_kernel(
    const __hip_bfloat16* __restrict__ qpb, const __hip_bfloat16* __restrict__ candb,
    const float* __restrict__ cn, int* __restrict__ topidx)
{
  // XCD-locality: round-robin dispatch puts same-b blocks on XCDs {b, b+4};
  // candb[b] (2.1 MB) then fits the per-XCD 4 MB L2.
  const int b = blockIdx.x & 3;
  const int split = (blockIdx.x >> 2) & 3;
  const int rt = blockIdx.x >> 4;          // 0..63
  const int row0 = rt * 16;
  const int tid = threadIdx.x;
  const int w = tid >> 6;          // wave 0..3
  const int lane = tid & 63;
  const int l15 = lane & 15;
  const int lg = lane >> 4;        // 0..3

  __shared__ unsigned md[16][16][17];   // [lane-list id][row][i], pad 17

  // B fragments: the block's 16 qp rows. Lane holds qp row (row0+l15), k=lg*8+s*32.
  short8 bfr[8];
  {
    const short* qrow = (const short*)qpb + ((size_t)(b * S_ + row0 + l15)) * D_ + lg * 8;
    #pragma unroll
    for (int s = 0; s < 8; ++s) bfr[s] = *(const short8*)(qrow + s * 32);
  }

  const float* cnb = cn + b * NC;
  const short* cbp = (const short*)candb + (size_t)b * NC * D_ + lg * 8;

  unsigned ld[16];
  #pragma unroll
  for (int i = 0; i < TOPN; ++i) ld[i] = 0xFFFFFFFFu;

  const int c0 = (split + 4 * w) * 16;
  const int ctail = split * 16 + C_;

  short8 aA[8], aB[8];
  #pragma unroll
  for (int s = 0; s < 8; ++s)
    aA[s] = *(const short8*)(cbp + (size_t)(c0 + l15) * D_ + s * 32);

  for (int j = 0; j < 8; ++j) {
    const int cA = c0 + 512 * j;
    const int cB = cA + 256;
    #pragma unroll
    for (int s = 0; s < 8; ++s)
      aB[s] = *(const short8*)(cbp + (size_t)(cB + l15) * D_ + s * 32);

    f32x4 acc = {0.f, 0.f, 0.f, 0.f};
    #pragma unroll
    for (int s = 0; s < 8; ++s)
      acc = __builtin_amdgcn_mfma_f32_16x16x32_bf16(aA[s], bfr[s], acc, 0, 0, 0);

    if (j < 7) {
      #pragma unroll
      for (int s = 0; s < 8; ++s)
        aA[s] = *(const short8*)(cbp + (size_t)(cA + 512 + l15) * D_ + s * 32);
    } else if (w == 3) {
      #pragma unroll
      for (int s = 0; s < 8; ++s)
        aA[s] = *(const short8*)(cbp + (size_t)(ctail + l15) * D_ + s * 32);
    }

    f32x4 acc2 = {0.f, 0.f, 0.f, 0.f};
    #pragma unroll
    for (int s = 0; s < 8; ++s)
      acc2 = __builtin_amdgcn_mfma_f32_16x16x32_bf16(aB[s], bfr[s], acc2, 0, 0, 0);

    // inserts after both chains: B-chain MFMAs co-issue with A-insert VALU
    INSERT_CANDS(acc, cA);
    INSERT_CANDS(acc2, cB);
  }
  if (w == 3) {   // memory-candidate group
    f32x4 acc = {0.f, 0.f, 0.f, 0.f};
    #pragma unroll
    for (int s = 0; s < 8; ++s)
      acc = __builtin_amdgcn_mfma_f32_16x16x32_bf16(aA[s], bfr[s], acc, 0, 0, 0);
    INSERT_CANDS(acc, ctail);
  }

  // dump per-lane key lists; merge 16 lists per row
  const int lid = w * 4 + lg;
  #pragma unroll
  for (int i = 0; i < TOPN; ++i) md[lid][l15][i] = ld[i];
  __syncthreads();

  if (tid < 16) {
    const int row = tid;
    unsigned fd[16];
    #pragma unroll
    for (int i = 0; i < TOPN; ++i) fd[i] = 0xFFFFFFFFu;
    for (int g = 0; g < 16; ++g) {
      for (int i = 0; i < TOPN; ++i) {
        const unsigned k = md[g][row][i];
        if (k >= fd[15]) break;   // per-g list sorted ascending
        fd[15] = k;
        #pragma unroll
        for (int s = 15; s > 0; --s) {
          if (fd[s] < fd[s - 1]) {
            unsigned t = fd[s]; fd[s] = fd[s - 1]; fd[s - 1] = t;
          }
        }
      }
    }
    int* dst = topidx + ((size_t)(b * S_ + row0 + row)) * CAND2 + split * TOPN;
    #pragma unroll
    for (int i = 0; i < TOPN; ++i) dst[i] = (int)(fd[i] & 0x1FFFu);
  }
}

// ---------------- pass 2: fp64 refine (UNCHANGED — bit-stable vs round 4) ----------------
__global__ __launch_bounds__(256) void refine_kernel(
    const double* __restrict__ qp64, const float* __restrict__ ctx,
    const float* __restrict__ mem, const int* __restrict__ topidx,
    float* __restrict__ out)
{
  const int row_global = blockIdx.x;
  const int tid = threadIdx.x;
  const int w = tid >> 6;         // wave 0..3: candidates [w*16, w*16+16)
  const int lane = tid & 63;
  const int c2 = lane >> 5;       // which cand of the pair
  const int ll = lane & 31;       // dim slice: [ll*8, ll*8+8)
  const int b = row_global >> 10;

  __shared__ double d2s[64];
  __shared__ int    ids_s[64];

  const double* qrow = qp64 + (size_t)row_global * D_;
  double qd[8];
  #pragma unroll
  for (int t = 0; t < 8; t += 2) {
    double2 v = *(const double2*)&qrow[ll * 8 + t];
    qd[t] = v.x; qd[t + 1] = v.y;
  }

  const int* tix = topidx + (size_t)row_global * CAND2 + w * 16;
  #pragma unroll 2
  for (int j = 0; j < 8; ++j) {
    const int p = 2 * j + c2;
    const int ci = tix[p];
    const float* cp = (ci < C_) ? ctx + ((size_t)b * C_ + ci) * D_
                                : mem + ((size_t)b * K_ + (ci - C_)) * D_;
    const float4 cv0 = *(const float4*)&cp[ll * 8];
    const float4 cv1 = *(const float4*)&cp[ll * 8 + 4];
    double a0 = 0.0, a1 = 0.0, df;
    df = qd[0] - (double)cv0.x; a0 = fma(df, df, a0);
    df = qd[1] - (double)cv0.y; a1 = fma(df, df, a1);
    df = qd[2] - (double)cv0.z; a0 = fma(df, df, a0);
    df = qd[3] - (double)cv0.w; a1 = fma(df, df, a1);
    df = qd[4] - (double)cv1.x; a0 = fma(df, df, a0);
    df = qd[5] - (double)cv1.y; a1 = fma(df, df, a1);
    df = qd[6] - (double)cv1.z; a0 = fma(df, df, a0);
    df = qd[7] - (double)cv1.w; a1 = fma(df, df, a1);
    double acc = a0 + a1;
    #pragma unroll
    for (int off = 16; off > 0; off >>= 1) acc += __shfl_down(acc, off, 32);
    if (ll == 0) { d2s[w * 16 + p] = acc; ids_s[w * 16 + p] = ci; }
  }
  __syncthreads();

  if (tid == 0) {
    double fd[TOPN]; int fi[TOPN];
    #pragma unroll
    for (int i = 0; i < TOPN; ++i) { fd[i] = DBL_MAX; fi[i] = 0x7fffffff; }
    for (int k2 = 0; k2 < CAND2; ++k2) {
      const double d2 = d2s[k2];
      const int c = ids_s[k2];
      if (d2 < fd[TOPN - 1] || (d2 == fd[TOPN - 1] && c < fi[TOPN - 1])) {
        fd[TOPN - 1] = d2; fi[TOPN - 1] = c;
        #pragma unroll
        for (int t = TOPN - 1; t > 0; --t) {
          if (fd[t] < fd[t - 1] || (fd[t] == fd[t - 1] && fi[t] < fi[t - 1])) {
            double td = fd[t]; fd[t] = fd[t - 1]; fd[t - 1] = td;
            int    ti = fi[t]; fi[t] = fi[t - 1]; fi[t - 1] = ti;
          }
        }
      }
    }
    const size_t obase = (size_t)row_global * TOPN;
    #pragma unroll
    for (int i = 0; i < TOPN; ++i) {
      out[obase + i] = (float)sqrt(fd[i] < 0.0 ? 0.0 : fd[i]);
      out[(size_t)B_ * S_ * TOPN + obase + i] = (float)fi[i];
    }
  }
}

extern "C" void kernel_launch(void* const* d_in, const int* in_sizes, int n_in,
                              void* d_out, int out_size, void* d_ws, size_t ws_size,
                              hipStream_t stream) {
  const float* q    = (const float*)d_in[0];
  const float* ctx  = (const float*)d_in[1];
  const float* mem  = (const float*)d_in[2];
  const float* W    = (const float*)d_in[3];
  const float* bias = (const float*)d_in[4];
  float* out = (float*)d_out;

  double* qp64 = (double*)d_ws;                                             // 8 MB
  __hip_bfloat16* qpb   = (__hip_bfloat16*)(qp64 + (size_t)B_ * S_ * D_);   // 2 MB
  __hip_bfloat16* candb = qpb + (size_t)B_ * S_ * D_;                       // 8.5 MB
  float* cn    = (float*)(candb + (size_t)B_ * NC * D_);                    // 66.5 KB
  int*   topidx = (int*)(cn + (size_t)B_ * NC);                             // 1 MB

  proj64_kernel<<<dim3(64, 4), 256, 0, stream>>>(q, W, bias, qp64, qpb);
  cvt_norm_kernel<<<(B_ * C_ * 64) / 256, 256, 0, stream>>>(ctx, candb, cn, 12, 0, 0);
  cvt_norm_kernel<<<(B_ * K_ * 64) / 256, 256, 0, stream>>>(mem, candb, cn, 6, C_ * D_, C_);
  dist_topk_kernel<<<1024, 256, 0, stream>>>(qpb, candb, cn, topidx);
  refine_kernel<<<B_ * S_, 256, 0, stream>>>(qp64, ctx, mem, topidx, out);
}

// Round 7
// 235.308 us; speedup vs baseline: 3.4502x; 1.0731x over previous
//
#include <hip/hip_runtime.h>
#include <hip/hip_bf16.h>
#include <cfloat>
#include <cmath>

#define B_ 4
#define S_ 1024
#define C_ 4096
#define K_ 64
#define D_ 256
#define NC 4160   // C_ + K_  (= 260 groups of 16)
#define TOPN 16
#define CAND2 64  // 4 splits x 16 candidates fed to fp64 refine

typedef __attribute__((ext_vector_type(8))) short short8;
typedef __attribute__((ext_vector_type(4))) float f32x4;

// ---------------- projection (fp64 accumulate) + bf16 copy of qp ----------------
__global__ __launch_bounds__(256) void proj64_kernel(
    const float* __restrict__ q, const float* __restrict__ W,
    const float* __restrict__ bias, double* __restrict__ qp64,
    __hip_bfloat16* __restrict__ qpb)
{
  __shared__ alignas(16) float As[64][36];
  __shared__ alignas(16) float Ws[64][36];
  const int tid = threadIdx.x;
  const int m0 = blockIdx.x * 64;
  const int n0 = blockIdx.y * 64;
  const int tx = tid & 15;
  const int ty = tid >> 4;
  const int lr = tid >> 3;
  const int lk = (tid & 7) * 4;
  double acc[4][4] = {};
  for (int k0 = 0; k0 < D_; k0 += 32) {
    __syncthreads();
    {
      float4 a0 = *(const float4*)&q[(size_t)(m0 + lr) * D_ + k0 + lk];
      float4 a1 = *(const float4*)&q[(size_t)(m0 + lr + 32) * D_ + k0 + lk];
      *(float4*)&As[lr][lk] = a0;
      *(float4*)&As[lr + 32][lk] = a1;
      float4 w0 = *(const float4*)&W[(size_t)(n0 + lr) * D_ + k0 + lk];
      float4 w1 = *(const float4*)&W[(size_t)(n0 + lr + 32) * D_ + k0 + lk];
      *(float4*)&Ws[lr][lk] = w0;
      *(float4*)&Ws[lr + 32][lk] = w1;
    }
    __syncthreads();
    #pragma unroll
    for (int kk = 0; kk < 32; kk += 4) {
      float4 av[4], wv[4];
      #pragma unroll
      for (int i = 0; i < 4; ++i) av[i] = *(const float4*)&As[ty * 4 + i][kk];
      #pragma unroll
      for (int j = 0; j < 4; ++j) wv[j] = *(const float4*)&Ws[tx + 16 * j][kk];
      #pragma unroll
      for (int i = 0; i < 4; ++i)
        #pragma unroll
        for (int j = 0; j < 4; ++j) {
          acc[i][j] = fma((double)av[i].x, (double)wv[j].x, acc[i][j]);
          acc[i][j] = fma((double)av[i].y, (double)wv[j].y, acc[i][j]);
          acc[i][j] = fma((double)av[i].z, (double)wv[j].z, acc[i][j]);
          acc[i][j] = fma((double)av[i].w, (double)wv[j].w, acc[i][j]);
        }
    }
  }
  #pragma unroll
  for (int i = 0; i < 4; ++i) {
    const int m = m0 + ty * 4 + i;
    #pragma unroll
    for (int j = 0; j < 4; ++j) {
      const int n = n0 + tx + 16 * j;
      const double v = acc[i][j] + (double)bias[n];
      qp64[(size_t)m * D_ + n] = v;
      qpb[(size_t)m * D_ + n] = __float2bfloat16((float)v);
    }
  }
}

// ---------------- fused fp32->bf16 cast + row squared-norms ----------------
__global__ __launch_bounds__(256) void cvt_norm_kernel(
    const float* __restrict__ src, __hip_bfloat16* __restrict__ dst,
    float* __restrict__ normp, int log2_rows_per_batch, int dst_base, int norm_base)
{
  const int e4 = blockIdx.x * 256 + threadIdx.x;   // float4 index
  const int row = e4 >> 6;
  const int b = row >> log2_rows_per_batch;
  const int r = row & ((1 << log2_rows_per_batch) - 1);
  const int k4 = e4 & 63;
  const float4 v = ((const float4*)src)[e4];
  __hip_bfloat16* d = dst + (size_t)b * (NC * D_) + dst_base + (size_t)r * D_ + k4 * 4;
  ushort4 o;
  __hip_bfloat16 h0 = __float2bfloat16(v.x); o.x = *(unsigned short*)&h0;
  __hip_bfloat16 h1 = __float2bfloat16(v.y); o.y = *(unsigned short*)&h1;
  __hip_bfloat16 h2 = __float2bfloat16(v.z); o.z = *(unsigned short*)&h2;
  __hip_bfloat16 h3 = __float2bfloat16(v.w); o.w = *(unsigned short*)&h3;
  *(ushort4*)d = o;
  float s = v.x * v.x + v.y * v.y + v.z * v.z + v.w * v.w;
  #pragma unroll
  for (int off = 32; off > 0; off >>= 1) s += __shfl_down(s, off);
  if ((threadIdx.x & 63) == 0) normp[b * NC + norm_base + r] = s;
}

// ---------------- pass 1: swapped-operand MFMA, packed-key top-16, parallel merge ----------------
// key = (float_bits(d2) & ~0x1FFF) | candidate_index; u32 order == d2 order
// (selection-only truncation, refine recomputes exact fp64).
#define INSERT_CANDS(ACC, CBASE)                                              \
  {                                                                           \
    const float4 cn4 = *(const float4*)&cnb[(CBASE) + lg * 4];                \
    _Pragma("unroll")                                                         \
    for (int r = 0; r < 4; ++r) {                                             \
      const float d2 = fmaf(-2.0f, (ACC)[r], ((const float*)&cn4)[r]);        \
      const unsigned key = (__float_as_uint(d2) & 0xFFFFE000u)                \
                           | (unsigned)((CBASE) + lg * 4 + r);                \
      if (key < ld[15]) {                                                     \
        ld[15] = key;                                                         \
        _Pragma("unroll")                                                     \
        for (int i = 15; i > 0; --i) {                                        \
          if (ld[i] < ld[i - 1]) {                                            \
            unsigned t = ld[i]; ld[i] = ld[i - 1]; ld[i - 1] = t;             \
          }                                                                   \
        }                                                                     \
      }                                                                       \
    }                                                                         \
  }

// dual-accumulator MFMA chain: halves dependent-MFMA latency
#define MFMA_CHAIN(ACC, FRAGS)                                                \
  f32x4 ACC;                                                                  \
  {                                                                           \
    f32x4 e_ = {0.f, 0.f, 0.f, 0.f}, o_ = {0.f, 0.f, 0.f, 0.f};              \
    _Pragma("unroll")                                                         \
    for (int s = 0; s < 8; s += 2) {                                          \
      e_ = __builtin_amdgcn_mfma_f32_16x16x32_bf16((FRAGS)[s], bfr[s], e_, 0, 0, 0);     \
      o_ = __builtin_amdgcn_mfma_f32_16x16x32_bf16((FRAGS)[s + 1], bfr[s + 1], o_, 0, 0, 0); \
    }                                                                         \
    ACC = e_ + o_;                                                            \
  }

__global__ __launch_bounds__(256) void dist_topk_kernel(
    const __hip_bfloat16* __restrict__ qpb, const __hip_bfloat16* __restrict__ candb,
    const float* __restrict__ cn, int* __restrict__ topidx)
{
  // XCD-locality: round-robin dispatch puts same-b blocks on XCDs {b, b+4};
  // candb[b] (2.1 MB) then fits the per-XCD 4 MB L2.
  const int b = blockIdx.x & 3;
  const int split = (blockIdx.x >> 2) & 3;
  const int rt = blockIdx.x >> 4;          // 0..63
  const int row0 = rt * 16;
  const int tid = threadIdx.x;
  const int w = tid >> 6;          // wave 0..3
  const int lane = tid & 63;
  const int l15 = lane & 15;
  const int lg = lane >> 4;        // 0..3

  __shared__ unsigned md[16][16][17];   // [row][list][entry], pad 17

  // B fragments: the block's 16 qp rows. Lane holds qp row (row0+l15), k=lg*8+s*32.
  short8 bfr[8];
  {
    const short* qrow = (const short*)qpb + ((size_t)(b * S_ + row0 + l15)) * D_ + lg * 8;
    #pragma unroll
    for (int s = 0; s < 8; ++s) bfr[s] = *(const short8*)(qrow + s * 32);
  }

  const float* cnb = cn + b * NC;
  const short* cbp = (const short*)candb + (size_t)b * NC * D_ + lg * 8;

  unsigned ld[16];
  #pragma unroll
  for (int i = 0; i < TOPN; ++i) ld[i] = 0xFFFFFFFFu;

  const int c0 = (split + 4 * w) * 16;
  const int ctail = split * 16 + C_;

  short8 aA[8], aB[8];
  #pragma unroll
  for (int s = 0; s < 8; ++s)
    aA[s] = *(const short8*)(cbp + (size_t)(c0 + l15) * D_ + s * 32);

  for (int j = 0; j < 8; ++j) {
    const int cA = c0 + 512 * j;
    const int cB = cA + 256;
    #pragma unroll
    for (int s = 0; s < 8; ++s)
      aB[s] = *(const short8*)(cbp + (size_t)(cB + l15) * D_ + s * 32);

    MFMA_CHAIN(acc, aA);

    if (j < 7) {
      #pragma unroll
      for (int s = 0; s < 8; ++s)
        aA[s] = *(const short8*)(cbp + (size_t)(cA + 512 + l15) * D_ + s * 32);
    } else if (w == 3) {
      #pragma unroll
      for (int s = 0; s < 8; ++s)
        aA[s] = *(const short8*)(cbp + (size_t)(ctail + l15) * D_ + s * 32);
    }

    MFMA_CHAIN(acc2, aB);

    // inserts after both chains: B-chain MFMAs co-issue with A-insert VALU
    INSERT_CANDS(acc, cA);
    INSERT_CANDS(acc2, cB);
  }
  if (w == 3) {   // memory-candidate group
    MFMA_CHAIN(acc, aA);
    INSERT_CANDS(acc, ctail);
  }

  // dump per-lane key lists: list id = w*4+lg, row = l15
  const int lid = w * 4 + lg;
  #pragma unroll
  for (int i = 0; i < TOPN; ++i) md[l15][lid][i] = ld[i];
  __syncthreads();

  // wave-parallel 16-way head-pointer merge: wave w merges rows 4w..4w+3.
  // 16-lane group per row; lane h owns sorted list h. 16 deterministic
  // iterations: shfl_xor min-reduce; unique winner (idx bits) advances.
  {
    const int g = lane >> 4;          // row-in-wave 0..3
    const int h = l15;                // list id
    const int row = w * 4 + g;
    int ptr = 0;
    unsigned cur = md[row][h][0];
    unsigned mykey = 0xFFFFFFFFu;     // lane h captures the h-th smallest
    #pragma unroll
    for (int it = 0; it < TOPN; ++it) {
      unsigned m = cur;
      #pragma unroll
      for (int off = 8; off > 0; off >>= 1) {
        const unsigned o = __shfl_xor(m, off, 16);
        m = (o < m) ? o : m;
      }
      if (h == it) mykey = m;
      if (cur == m) {                 // unique winner advances its head
        ++ptr;
        cur = (ptr < TOPN) ? md[row][h][ptr] : 0xFFFFFFFFu;
      }
    }
    int* dst = topidx + ((size_t)(b * S_ + row0 + row)) * CAND2 + split * TOPN;
    dst[h] = (int)(mykey & 0x1FFFu);
  }
}

// ---------------- pass 2: fp64 refine (UNCHANGED — bit-stable) ----------------
__global__ __launch_bounds__(256) void refine_kernel(
    const double* __restrict__ qp64, const float* __restrict__ ctx,
    const float* __restrict__ mem, const int* __restrict__ topidx,
    float* __restrict__ out)
{
  const int row_global = blockIdx.x;
  const int tid = threadIdx.x;
  const int w = tid >> 6;         // wave 0..3: candidates [w*16, w*16+16)
  const int lane = tid & 63;
  const int c2 = lane >> 5;       // which cand of the pair
  const int ll = lane & 31;       // dim slice: [ll*8, ll*8+8)
  const int b = row_global >> 10;

  __shared__ double d2s[64];
  __shared__ int    ids_s[64];

  const double* qrow = qp64 + (size_t)row_global * D_;
  double qd[8];
  #pragma unroll
  for (int t = 0; t < 8; t += 2) {
    double2 v = *(const double2*)&qrow[ll * 8 + t];
    qd[t] = v.x; qd[t + 1] = v.y;
  }

  const int* tix = topidx + (size_t)row_global * CAND2 + w * 16;
  #pragma unroll 2
  for (int j = 0; j < 8; ++j) {
    const int p = 2 * j + c2;
    const int ci = tix[p];
    const float* cp = (ci < C_) ? ctx + ((size_t)b * C_ + ci) * D_
                                : mem + ((size_t)b * K_ + (ci - C_)) * D_;
    const float4 cv0 = *(const float4*)&cp[ll * 8];
    const float4 cv1 = *(const float4*)&cp[ll * 8 + 4];
    double a0 = 0.0, a1 = 0.0, df;
    df = qd[0] - (double)cv0.x; a0 = fma(df, df, a0);
    df = qd[1] - (double)cv0.y; a1 = fma(df, df, a1);
    df = qd[2] - (double)cv0.z; a0 = fma(df, df, a0);
    df = qd[3] - (double)cv0.w; a1 = fma(df, df, a1);
    df = qd[4] - (double)cv1.x; a0 = fma(df, df, a0);
    df = qd[5] - (double)cv1.y; a1 = fma(df, df, a1);
    df = qd[6] - (double)cv1.z; a0 = fma(df, df, a0);
    df = qd[7] - (double)cv1.w; a1 = fma(df, df, a1);
    double acc = a0 + a1;
    #pragma unroll
    for (int off = 16; off > 0; off >>= 1) acc += __shfl_down(acc, off, 32);
    if (ll == 0) { d2s[w * 16 + p] = acc; ids_s[w * 16 + p] = ci; }
  }
  __syncthreads();

  if (tid == 0) {
    double fd[TOPN]; int fi[TOPN];
    #pragma unroll
    for (int i = 0; i < TOPN; ++i) { fd[i] = DBL_MAX; fi[i] = 0x7fffffff; }
    for (int k2 = 0; k2 < CAND2; ++k2) {
      const double d2 = d2s[k2];
      const int c = ids_s[k2];
      if (d2 < fd[TOPN - 1] || (d2 == fd[TOPN - 1] && c < fi[TOPN - 1])) {
        fd[TOPN - 1] = d2; fi[TOPN - 1] = c;
        #pragma unroll
        for (int t = TOPN - 1; t > 0; --t) {
          if (fd[t] < fd[t - 1] || (fd[t] == fd[t - 1] && fi[t] < fi[t - 1])) {
            double td = fd[t]; fd[t] = fd[t - 1]; fd[t - 1] = td;
            int    ti = fi[t]; fi[t] = fi[t - 1]; fi[t - 1] = ti;
          }
        }
      }
    }
    const size_t obase = (size_t)row_global * TOPN;
    #pragma unroll
    for (int i = 0; i < TOPN; ++i) {
      out[obase + i] = (float)sqrt(fd[i] < 0.0 ? 0.0 : fd[i]);
      out[(size_t)B_ * S_ * TOPN + obase + i] = (float)fi[i];
    }
  }
}

extern "C" void kernel_launch(void* const* d_in, const int* in_sizes, int n_in,
                              void* d_out, int out_size, void* d_ws, size_t ws_size,
                              hipStream_t stream) {
  const float* q    = (const float*)d_in[0];
  const float* ctx  = (const float*)d_in[1];
  const float* mem  = (const float*)d_in[2];
  const float* W    = (const float*)d_in[3];
  const float* bias = (const float*)d_in[4];
  float* out = (float*)d_out;

  double* qp64 = (double*)d_ws;                                             // 8 MB
  __hip_bfloat16* qpb   = (__hip_bfloat16*)(qp64 + (size_t)B_ * S_ * D_);   // 2 MB
  __hip_bfloat16* candb = qpb + (size_t)B_ * S_ * D_;                       // 8.5 MB
  float* cn    = (float*)(candb + (size_t)B_ * NC * D_);                    // 66.5 KB
  int*   topidx = (int*)(cn + (size_t)B_ * NC);                             // 1 MB

  proj64_kernel<<<dim3(64, 4), 256, 0, stream>>>(q, W, bias, qp64, qpb);
  cvt_norm_kernel<<<(B_ * C_ * 64) / 256, 256, 0, stream>>>(ctx, candb, cn, 12, 0, 0);
  cvt_norm_kernel<<<(B_ * K_ * 64) / 256, 256, 0, stream>>>(mem, candb, cn, 6, C_ * D_, C_);
  dist_topk_kernel<<<1024, 256, 0, stream>>>(qpb, candb, cn, topidx);
  refine_kernel<<<B_ * S_, 256, 0, stream>>>(qp64, ctx, mem, topidx, out);
}

// Round 8
// 153.693 us; speedup vs baseline: 5.2824x; 1.5310x over previous
//
#include <hip/hip_runtime.h>
#include <hip/hip_bf16.h>
#include <cfloat>
#include <cmath>

#define B_ 4
#define S_ 1024
#define C_ 4096
#define K_ 64
#define D_ 256
#define NC 4160   // C_ + K_  (= 260 groups of 16)
#define TOPN 16
#define CAND2 64  // 4 splits x 16 candidates fed to fp64 refine

typedef __attribute__((ext_vector_type(8))) short short8;
typedef __attribute__((ext_vector_type(4))) float f32x4;

// ---------------- projection (fp64 accumulate) + bf16 copy of qp ----------------
__global__ __launch_bounds__(256) void proj64_kernel(
    const float* __restrict__ q, const float* __restrict__ W,
    const float* __restrict__ bias, double* __restrict__ qp64,
    __hip_bfloat16* __restrict__ qpb)
{
  __shared__ alignas(16) float As[64][36];
  __shared__ alignas(16) float Ws[64][36];
  const int tid = threadIdx.x;
  const int m0 = blockIdx.x * 64;
  const int n0 = blockIdx.y * 64;
  const int tx = tid & 15;
  const int ty = tid >> 4;
  const int lr = tid >> 3;
  const int lk = (tid & 7) * 4;
  double acc[4][4] = {};
  for (int k0 = 0; k0 < D_; k0 += 32) {
    __syncthreads();
    {
      float4 a0 = *(const float4*)&q[(size_t)(m0 + lr) * D_ + k0 + lk];
      float4 a1 = *(const float4*)&q[(size_t)(m0 + lr + 32) * D_ + k0 + lk];
      *(float4*)&As[lr][lk] = a0;
      *(float4*)&As[lr + 32][lk] = a1;
      float4 w0 = *(const float4*)&W[(size_t)(n0 + lr) * D_ + k0 + lk];
      float4 w1 = *(const float4*)&W[(size_t)(n0 + lr + 32) * D_ + k0 + lk];
      *(float4*)&Ws[lr][lk] = w0;
      *(float4*)&Ws[lr + 32][lk] = w1;
    }
    __syncthreads();
    #pragma unroll
    for (int kk = 0; kk < 32; kk += 4) {
      float4 av[4], wv[4];
      #pragma unroll
      for (int i = 0; i < 4; ++i) av[i] = *(const float4*)&As[ty * 4 + i][kk];
      #pragma unroll
      for (int j = 0; j < 4; ++j) wv[j] = *(const float4*)&Ws[tx + 16 * j][kk];
      #pragma unroll
      for (int i = 0; i < 4; ++i)
        #pragma unroll
        for (int j = 0; j < 4; ++j) {
          acc[i][j] = fma((double)av[i].x, (double)wv[j].x, acc[i][j]);
          acc[i][j] = fma((double)av[i].y, (double)wv[j].y, acc[i][j]);
          acc[i][j] = fma((double)av[i].z, (double)wv[j].z, acc[i][j]);
          acc[i][j] = fma((double)av[i].w, (double)wv[j].w, acc[i][j]);
        }
    }
  }
  #pragma unroll
  for (int i = 0; i < 4; ++i) {
    const int m = m0 + ty * 4 + i;
    #pragma unroll
    for (int j = 0; j < 4; ++j) {
      const int n = n0 + tx + 16 * j;
      const double v = acc[i][j] + (double)bias[n];
      qp64[(size_t)m * D_ + n] = v;
      qpb[(size_t)m * D_ + n] = __float2bfloat16((float)v);
    }
  }
}

// ---------------- fused fp32->bf16 cast + row squared-norms ----------------
__global__ __launch_bounds__(256) void cvt_norm_kernel(
    const float* __restrict__ src, __hip_bfloat16* __restrict__ dst,
    float* __restrict__ normp, int log2_rows_per_batch, int dst_base, int norm_base)
{
  const int e4 = blockIdx.x * 256 + threadIdx.x;   // float4 index
  const int row = e4 >> 6;
  const int b = row >> log2_rows_per_batch;
  const int r = row & ((1 << log2_rows_per_batch) - 1);
  const int k4 = e4 & 63;
  const float4 v = ((const float4*)src)[e4];
  __hip_bfloat16* d = dst + (size_t)b * (NC * D_) + dst_base + (size_t)r * D_ + k4 * 4;
  ushort4 o;
  __hip_bfloat16 h0 = __float2bfloat16(v.x); o.x = *(unsigned short*)&h0;
  __hip_bfloat16 h1 = __float2bfloat16(v.y); o.y = *(unsigned short*)&h1;
  __hip_bfloat16 h2 = __float2bfloat16(v.z); o.z = *(unsigned short*)&h2;
  __hip_bfloat16 h3 = __float2bfloat16(v.w); o.w = *(unsigned short*)&h3;
  *(ushort4*)d = o;
  float s = v.x * v.x + v.y * v.y + v.z * v.z + v.w * v.w;
  #pragma unroll
  for (int off = 32; off > 0; off >>= 1) s += __shfl_down(s, off);
  if ((threadIdx.x & 63) == 0) normp[b * NC + norm_base + r] = s;
}

// ---------------- pass 1: swapped-operand MFMA, packed-key top-16, parallel merge ----------------
#define INSERT_CANDS(ACC, CBASE)                                              \
  {                                                                           \
    const float4 cn4 = *(const float4*)&cnb[(CBASE) + lg * 4];                \
    _Pragma("unroll")                                                         \
    for (int r = 0; r < 4; ++r) {                                             \
      const float d2 = fmaf(-2.0f, (ACC)[r], ((const float*)&cn4)[r]);        \
      const unsigned key = (__float_as_uint(d2) & 0xFFFFE000u)                \
                           | (unsigned)((CBASE) + lg * 4 + r);                \
      if (key < ld[15]) {                                                     \
        ld[15] = key;                                                         \
        _Pragma("unroll")                                                     \
        for (int i = 15; i > 0; --i) {                                        \
          if (ld[i] < ld[i - 1]) {                                            \
            unsigned t = ld[i]; ld[i] = ld[i - 1]; ld[i - 1] = t;             \
          }                                                                   \
        }                                                                     \
      }                                                                       \
    }                                                                         \
  }

#define MFMA_CHAIN(ACC, FRAGS)                                                \
  f32x4 ACC;                                                                  \
  {                                                                           \
    f32x4 e_ = {0.f, 0.f, 0.f, 0.f}, o_ = {0.f, 0.f, 0.f, 0.f};              \
    _Pragma("unroll")                                                         \
    for (int s = 0; s < 8; s += 2) {                                          \
      e_ = __builtin_amdgcn_mfma_f32_16x16x32_bf16((FRAGS)[s], bfr[s], e_, 0, 0, 0);     \
      o_ = __builtin_amdgcn_mfma_f32_16x16x32_bf16((FRAGS)[s + 1], bfr[s + 1], o_, 0, 0, 0); \
    }                                                                         \
    ACC = e_ + o_;                                                            \
  }

__global__ __launch_bounds__(256) void dist_topk_kernel(
    const __hip_bfloat16* __restrict__ qpb, const __hip_bfloat16* __restrict__ candb,
    const float* __restrict__ cn, int* __restrict__ topidx)
{
  const int b = blockIdx.x & 3;
  const int split = (blockIdx.x >> 2) & 3;
  const int rt = blockIdx.x >> 4;          // 0..63
  const int row0 = rt * 16;
  const int tid = threadIdx.x;
  const int w = tid >> 6;          // wave 0..3
  const int lane = tid & 63;
  const int l15 = lane & 15;
  const int lg = lane >> 4;        // 0..3

  __shared__ unsigned md[16][16][17];   // [row][list][entry], pad 17

  short8 bfr[8];
  {
    const short* qrow = (const short*)qpb + ((size_t)(b * S_ + row0 + l15)) * D_ + lg * 8;
    #pragma unroll
    for (int s = 0; s < 8; ++s) bfr[s] = *(const short8*)(qrow + s * 32);
  }

  const float* cnb = cn + b * NC;
  const short* cbp = (const short*)candb + (size_t)b * NC * D_ + lg * 8;

  unsigned ld[16];
  #pragma unroll
  for (int i = 0; i < TOPN; ++i) ld[i] = 0xFFFFFFFFu;

  const int c0 = (split + 4 * w) * 16;
  const int ctail = split * 16 + C_;

  short8 aA[8], aB[8];
  #pragma unroll
  for (int s = 0; s < 8; ++s)
    aA[s] = *(const short8*)(cbp + (size_t)(c0 + l15) * D_ + s * 32);

  for (int j = 0; j < 8; ++j) {
    const int cA = c0 + 512 * j;
    const int cB = cA + 256;
    #pragma unroll
    for (int s = 0; s < 8; ++s)
      aB[s] = *(const short8*)(cbp + (size_t)(cB + l15) * D_ + s * 32);

    MFMA_CHAIN(acc, aA);

    if (j < 7) {
      #pragma unroll
      for (int s = 0; s < 8; ++s)
        aA[s] = *(const short8*)(cbp + (size_t)(cA + 512 + l15) * D_ + s * 32);
    } else if (w == 3) {
      #pragma unroll
      for (int s = 0; s < 8; ++s)
        aA[s] = *(const short8*)(cbp + (size_t)(ctail + l15) * D_ + s * 32);
    }

    MFMA_CHAIN(acc2, aB);

    INSERT_CANDS(acc, cA);
    INSERT_CANDS(acc2, cB);
  }
  if (w == 3) {   // memory-candidate group
    MFMA_CHAIN(acc, aA);
    INSERT_CANDS(acc, ctail);
  }

  const int lid = w * 4 + lg;
  #pragma unroll
  for (int i = 0; i < TOPN; ++i) md[l15][lid][i] = ld[i];
  __syncthreads();

  {
    const int g = lane >> 4;          // row-in-wave 0..3
    const int h = l15;                // list id
    const int row = w * 4 + g;
    int ptr = 0;
    unsigned cur = md[row][h][0];
    unsigned mykey = 0xFFFFFFFFu;     // lane h captures the h-th smallest
    #pragma unroll
    for (int it = 0; it < TOPN; ++it) {
      unsigned m = cur;
      #pragma unroll
      for (int off = 8; off > 0; off >>= 1) {
        const unsigned o = __shfl_xor(m, off, 16);
        m = (o < m) ? o : m;
      }
      if (h == it) mykey = m;
      if (cur == m) {                 // unique winner advances its head
        ++ptr;
        cur = (ptr < TOPN) ? md[row][h][ptr] : 0xFFFFFFFFu;
      }
    }
    int* dst = topidx + ((size_t)(b * S_ + row0 + row)) * CAND2 + split * TOPN;
    dst[h] = (int)(mykey & 0x1FFFu);
  }
}

// ---------------- pass 2: fp64 refine — preloaded loads + parallel bitonic top-16 ----------------
__global__ __launch_bounds__(256) void refine_kernel(
    const double* __restrict__ qp64, const float* __restrict__ ctx,
    const float* __restrict__ mem, const int* __restrict__ topidx,
    float* __restrict__ out)
{
  const int row_global = blockIdx.x;
  const int tid = threadIdx.x;
  const int w = tid >> 6;         // wave 0..3: candidates [w*16, w*16+16)
  const int lane = tid & 63;
  const int c2 = lane >> 5;       // which cand of the pair
  const int ll = lane & 31;       // dim slice: [ll*8, ll*8+8)
  const int b = row_global >> 10;

  __shared__ double d2s[64];
  __shared__ int    ids_s[64];

  const double* qrow = qp64 + (size_t)row_global * D_;
  double qd[8];
  #pragma unroll
  for (int t = 0; t < 8; t += 2) {
    double2 v = *(const double2*)&qrow[ll * 8 + t];
    qd[t] = v.x; qd[t + 1] = v.y;
  }

  // hoist all candidate loads: 8 pairs -> 16 float4 loads in flight per lane
  const int* tix = topidx + (size_t)row_global * CAND2 + w * 16;
  int cis[8];
  #pragma unroll
  for (int j = 0; j < 8; ++j) cis[j] = tix[2 * j + c2];
  float4 cva[8], cvb[8];
  #pragma unroll
  for (int j = 0; j < 8; ++j) {
    const int ci = cis[j];
    const float* cp = (ci < C_) ? ctx + ((size_t)b * C_ + ci) * D_
                                : mem + ((size_t)b * K_ + (ci - C_)) * D_;
    cva[j] = *(const float4*)&cp[ll * 8];
    cvb[j] = *(const float4*)&cp[ll * 8 + 4];
  }

  #pragma unroll
  for (int j = 0; j < 8; ++j) {
    double a0 = 0.0, a1 = 0.0, df;
    df = qd[0] - (double)cva[j].x; a0 = fma(df, df, a0);
    df = qd[1] - (double)cva[j].y; a1 = fma(df, df, a1);
    df = qd[2] - (double)cva[j].z; a0 = fma(df, df, a0);
    df = qd[3] - (double)cva[j].w; a1 = fma(df, df, a1);
    df = qd[4] - (double)cvb[j].x; a0 = fma(df, df, a0);
    df = qd[5] - (double)cvb[j].y; a1 = fma(df, df, a1);
    df = qd[6] - (double)cvb[j].z; a0 = fma(df, df, a0);
    df = qd[7] - (double)cvb[j].w; a1 = fma(df, df, a1);
    double acc = a0 + a1;
    #pragma unroll
    for (int off = 16; off > 0; off >>= 1) acc += __shfl_down(acc, off, 32);
    if (ll == 0) { d2s[w * 16 + 2 * j + c2] = acc; ids_s[w * 16 + 2 * j + c2] = cis[j]; }
  }
  __syncthreads();

  // wave 0: exact bitonic sort of 64 (d2, idx) pairs, lexicographic (d2, idx).
  // All indices distinct -> strict total order -> identical result to the
  // serial insertion scan (same fp64 values, same tie-break).
  if (w == 0) {
    double d2 = d2s[lane];
    int    ci = ids_s[lane];
    #pragma unroll
    for (int k = 2; k <= 64; k <<= 1) {
      #pragma unroll
      for (int j2 = k >> 1; j2 > 0; j2 >>= 1) {
        const double od2 = __shfl_xor(d2, j2);
        const int    oci = __shfl_xor(ci, j2);
        const bool up = ((lane & k) == 0);               // ascending segment
        const bool less = (d2 < od2) || (d2 == od2 && ci < oci);
        const bool keep_min = (((lane & j2) == 0) == up);
        const bool take = keep_min ? !less : less;
        if (take) { d2 = od2; ci = oci; }
      }
    }
    if (lane < TOPN) {
      const size_t obase = (size_t)row_global * TOPN;
      out[obase + lane] = (float)sqrt(d2 < 0.0 ? 0.0 : d2);
      out[(size_t)B_ * S_ * TOPN + obase + lane] = (float)ci;
    }
  }
}

extern "C" void kernel_launch(void* const* d_in, const int* in_sizes, int n_in,
                              void* d_out, int out_size, void* d_ws, size_t ws_size,
                              hipStream_t stream) {
  const float* q    = (const float*)d_in[0];
  const float* ctx  = (const float*)d_in[1];
  const float* mem  = (const float*)d_in[2];
  const float* W    = (const float*)d_in[3];
  const float* bias = (const float*)d_in[4];
  float* out = (float*)d_out;

  double* qp64 = (double*)d_ws;                                             // 8 MB
  __hip_bfloat16* qpb   = (__hip_bfloat16*)(qp64 + (size_t)B_ * S_ * D_);   // 2 MB
  __hip_bfloat16* candb = qpb + (size_t)B_ * S_ * D_;                       // 8.5 MB
  float* cn    = (float*)(candb + (size_t)B_ * NC * D_);                    // 66.5 KB
  int*   topidx = (int*)(cn + (size_t)B_ * NC);                             // 1 MB

  proj64_kernel<<<dim3(64, 4), 256, 0, stream>>>(q, W, bias, qp64, qpb);
  cvt_norm_kernel<<<(B_ * C_ * 64) / 256, 256, 0, stream>>>(ctx, candb, cn, 12, 0, 0);
  cvt_norm_kernel<<<(B_ * K_ * 64) / 256, 256, 0, stream>>>(mem, candb, cn, 6, C_ * D_, C_);
  dist_topk_kernel<<<1024, 256, 0, stream>>>(qpb, candb, cn, topidx);
  refine_kernel<<<B_ * S_, 256, 0, stream>>>(qp64, ctx, mem, topidx, out);
}

// Round 9
// 110.327 us; speedup vs baseline: 7.3587x; 1.3931x over previous
//
#include <hip/hip_runtime.h>
#include <hip/hip_bf16.h>
#include <cfloat>
#include <cmath>

#define B_ 4
#define S_ 1024
#define C_ 4096
#define K_ 64
#define D_ 256
#define NC 4160   // C_ + K_  (= 260 groups of 16)
#define TOPN 16
#define CAND2 64  // 4 splits x 16 candidates fed to fp64 refine

typedef __attribute__((ext_vector_type(8))) short short8;
typedef __attribute__((ext_vector_type(4))) float f32x4;

// ---------------- projection (fp64 accumulate) + bf16 copy of qp ----------------
__global__ __launch_bounds__(256) void proj64_kernel(
    const float* __restrict__ q, const float* __restrict__ W,
    const float* __restrict__ bias, double* __restrict__ qp64,
    __hip_bfloat16* __restrict__ qpb)
{
  __shared__ alignas(16) float As[64][36];
  __shared__ alignas(16) float Ws[64][36];
  const int tid = threadIdx.x;
  const int m0 = blockIdx.x * 64;
  const int n0 = blockIdx.y * 64;
  const int tx = tid & 15;
  const int ty = tid >> 4;
  const int lr = tid >> 3;
  const int lk = (tid & 7) * 4;
  double acc[4][4] = {};
  for (int k0 = 0; k0 < D_; k0 += 32) {
    __syncthreads();
    {
      float4 a0 = *(const float4*)&q[(size_t)(m0 + lr) * D_ + k0 + lk];
      float4 a1 = *(const float4*)&q[(size_t)(m0 + lr + 32) * D_ + k0 + lk];
      *(float4*)&As[lr][lk] = a0;
      *(float4*)&As[lr + 32][lk] = a1;
      float4 w0 = *(const float4*)&W[(size_t)(n0 + lr) * D_ + k0 + lk];
      float4 w1 = *(const float4*)&W[(size_t)(n0 + lr + 32) * D_ + k0 + lk];
      *(float4*)&Ws[lr][lk] = w0;
      *(float4*)&Ws[lr + 32][lk] = w1;
    }
    __syncthreads();
    #pragma unroll
    for (int kk = 0; kk < 32; kk += 4) {
      float4 av[4], wv[4];
      #pragma unroll
      for (int i = 0; i < 4; ++i) av[i] = *(const float4*)&As[ty * 4 + i][kk];
      #pragma unroll
      for (int j = 0; j < 4; ++j) wv[j] = *(const float4*)&Ws[tx + 16 * j][kk];
      #pragma unroll
      for (int i = 0; i < 4; ++i)
        #pragma unroll
        for (int j = 0; j < 4; ++j) {
          acc[i][j] = fma((double)av[i].x, (double)wv[j].x, acc[i][j]);
          acc[i][j] = fma((double)av[i].y, (double)wv[j].y, acc[i][j]);
          acc[i][j] = fma((double)av[i].z, (double)wv[j].z, acc[i][j]);
          acc[i][j] = fma((double)av[i].w, (double)wv[j].w, acc[i][j]);
        }
    }
  }
  #pragma unroll
  for (int i = 0; i < 4; ++i) {
    const int m = m0 + ty * 4 + i;
    #pragma unroll
    for (int j = 0; j < 4; ++j) {
      const int n = n0 + tx + 16 * j;
      const double v = acc[i][j] + (double)bias[n];
      qp64[(size_t)m * D_ + n] = v;
      qpb[(size_t)m * D_ + n] = __float2bfloat16((float)v);
    }
  }
}

// ---------------- fused fp32->bf16 cast (FRAGMENT-MAJOR layout) + row norms ----------------
// dst layout per batch: group g (16 cands) -> [g][s(0..7)][lg(0..3)][l15(0..15)][8 shorts].
// Element (cand row R, dim k): g=R>>4, l15=R&15, s=k>>5, lg=(k&31)>>3, i=k&7.
__global__ __launch_bounds__(256) void cvt_norm_kernel(
    const float* __restrict__ src, unsigned short* __restrict__ dst,
    float* __restrict__ normp, int log2_rows_per_batch, int dst_row_base, int norm_base)
{
  const int e4 = blockIdx.x * 256 + threadIdx.x;   // float4 index
  const int row = e4 >> 6;
  const int b = row >> log2_rows_per_batch;
  const int r = row & ((1 << log2_rows_per_batch) - 1);
  const int k4 = e4 & 63;
  const float4 v = ((const float4*)src)[e4];
  const int R = dst_row_base + r;
  const int g = R >> 4, l15 = R & 15;
  const int k = k4 * 4;
  const int s = k >> 5, lg = (k & 31) >> 3, i = k & 7;
  unsigned short* d = dst + (size_t)b * (NC * D_) +
                      (size_t)g * 4096 + s * 512 + lg * 128 + l15 * 8 + i;
  ushort4 o;
  __hip_bfloat16 h0 = __float2bfloat16(v.x); o.x = *(unsigned short*)&h0;
  __hip_bfloat16 h1 = __float2bfloat16(v.y); o.y = *(unsigned short*)&h1;
  __hip_bfloat16 h2 = __float2bfloat16(v.z); o.z = *(unsigned short*)&h2;
  __hip_bfloat16 h3 = __float2bfloat16(v.w); o.w = *(unsigned short*)&h3;
  *(ushort4*)d = o;
  float sacc = v.x * v.x + v.y * v.y + v.z * v.z + v.w * v.w;
  #pragma unroll
  for (int off = 32; off > 0; off >>= 1) sacc += __shfl_down(sacc, off);
  if ((threadIdx.x & 63) == 0) normp[b * NC + norm_base + r] = sacc;
}

// ---------------- pass 1: swapped-operand MFMA, packed-key top-16, parallel merge ----------------
#define INSERT_CANDS(ACC, CBASE)                                              \
  {                                                                           \
    const float4 cn4 = *(const float4*)&cnb[(CBASE) + lg * 4];                \
    _Pragma("unroll")                                                         \
    for (int r = 0; r < 4; ++r) {                                             \
      const float d2 = fmaf(-2.0f, (ACC)[r], ((const float*)&cn4)[r]);        \
      const unsigned key = (__float_as_uint(d2) & 0xFFFFE000u)                \
                           | (unsigned)((CBASE) + lg * 4 + r);                \
      if (key < ld[15]) {                                                     \
        ld[15] = key;                                                         \
        _Pragma("unroll")                                                     \
        for (int i = 15; i > 0; --i) {                                        \
          if (ld[i] < ld[i - 1]) {                                            \
            unsigned t = ld[i]; ld[i] = ld[i - 1]; ld[i - 1] = t;             \
          }                                                                   \
        }                                                                     \
      }                                                                       \
    }                                                                         \
  }

#define MFMA_CHAIN(ACC, FRAGS)                                                \
  f32x4 ACC;                                                                  \
  {                                                                           \
    f32x4 e_ = {0.f, 0.f, 0.f, 0.f}, o_ = {0.f, 0.f, 0.f, 0.f};              \
    _Pragma("unroll")                                                         \
    for (int s = 0; s < 8; s += 2) {                                          \
      e_ = __builtin_amdgcn_mfma_f32_16x16x32_bf16((FRAGS)[s], bfr[s], e_, 0, 0, 0);     \
      o_ = __builtin_amdgcn_mfma_f32_16x16x32_bf16((FRAGS)[s + 1], bfr[s + 1], o_, 0, 0, 0); \
    }                                                                         \
    ACC = e_ + o_;                                                            \
  }

__global__ __launch_bounds__(256) void dist_topk_kernel(
    const __hip_bfloat16* __restrict__ qpb, const unsigned short* __restrict__ candb,
    const float* __restrict__ cn, int* __restrict__ topidx)
{
  const int b = blockIdx.x & 3;
  const int split = (blockIdx.x >> 2) & 3;
  const int rt = blockIdx.x >> 4;          // 0..63
  const int row0 = rt * 16;
  const int tid = threadIdx.x;
  const int w = tid >> 6;          // wave 0..3
  const int lane = tid & 63;
  const int l15 = lane & 15;
  const int lg = lane >> 4;        // 0..3

  __shared__ unsigned md[16][16][17];   // [row][list][entry], pad 17

  short8 bfr[8];
  {
    const short* qrow = (const short*)qpb + ((size_t)(b * S_ + row0 + l15)) * D_ + lg * 8;
    #pragma unroll
    for (int s = 0; s < 8; ++s) bfr[s] = *(const short8*)(qrow + s * 32);
  }

  const float* cnb = cn + b * NC;
  // fragment-major base: lane offset lg*128 + l15*8 -> wave reads 1KB contiguous per frag
  const short* cbp = (const short*)candb + (size_t)b * NC * D_ + lg * 128 + l15 * 8;

  unsigned ld[16];
  #pragma unroll
  for (int i = 0; i < TOPN; ++i) ld[i] = 0xFFFFFFFFu;

  const int gbase = split + 4 * w;     // group id; candidate base = g*16
  const int gtail = 256 + split;

  short8 aA[8], aB[8];
  #pragma unroll
  for (int s = 0; s < 8; ++s)
    aA[s] = *(const short8*)(cbp + (size_t)gbase * 4096 + s * 512);

  for (int j = 0; j < 8; ++j) {
    const int gA = gbase + 32 * j;
    const int gB = gA + 16;
    #pragma unroll
    for (int s = 0; s < 8; ++s)
      aB[s] = *(const short8*)(cbp + (size_t)gB * 4096 + s * 512);

    MFMA_CHAIN(acc, aA);

    if (j < 7) {
      #pragma unroll
      for (int s = 0; s < 8; ++s)
        aA[s] = *(const short8*)(cbp + (size_t)(gA + 32) * 4096 + s * 512);
    } else if (w == 3) {
      #pragma unroll
      for (int s = 0; s < 8; ++s)
        aA[s] = *(const short8*)(cbp + (size_t)gtail * 4096 + s * 512);
    }

    MFMA_CHAIN(acc2, aB);

    INSERT_CANDS(acc, gA * 16);
    INSERT_CANDS(acc2, gB * 16);
  }
  if (w == 3) {   // memory-candidate group
    MFMA_CHAIN(acc, aA);
    INSERT_CANDS(acc, gtail * 16);
  }

  const int lid = w * 4 + lg;
  #pragma unroll
  for (int i = 0; i < TOPN; ++i) md[l15][lid][i] = ld[i];
  __syncthreads();

  {
    const int g = lane >> 4;          // row-in-wave 0..3
    const int h = l15;                // list id
    const int row = w * 4 + g;
    int ptr = 0;
    unsigned cur = md[row][h][0];
    unsigned mykey = 0xFFFFFFFFu;     // lane h captures the h-th smallest
    #pragma unroll
    for (int it = 0; it < TOPN; ++it) {
      unsigned m = cur;
      #pragma unroll
      for (int off = 8; off > 0; off >>= 1) {
        const unsigned o = __shfl_xor(m, off, 16);
        m = (o < m) ? o : m;
      }
      if (h == it) mykey = m;
      if (cur == m) {                 // unique winner advances its head
        ++ptr;
        cur = (ptr < TOPN) ? md[row][h][ptr] : 0xFFFFFFFFu;
      }
    }
    int* dst = topidx + ((size_t)(b * S_ + row0 + row)) * CAND2 + split * TOPN;
    dst[h] = (int)(mykey & 0x1FFFu);
  }
}

// ---------------- pass 2: fp64 refine — preloaded loads + parallel bitonic top-16 ----------------
__global__ __launch_bounds__(256) void refine_kernel(
    const double* __restrict__ qp64, const float* __restrict__ ctx,
    const float* __restrict__ mem, const int* __restrict__ topidx,
    float* __restrict__ out)
{
  const int row_global = blockIdx.x;
  const int tid = threadIdx.x;
  const int w = tid >> 6;         // wave 0..3: candidates [w*16, w*16+16)
  const int lane = tid & 63;
  const int c2 = lane >> 5;       // which cand of the pair
  const int ll = lane & 31;       // dim slice: [ll*8, ll*8+8)
  const int b = row_global >> 10;

  __shared__ double d2s[64];
  __shared__ int    ids_s[64];

  const double* qrow = qp64 + (size_t)row_global * D_;
  double qd[8];
  #pragma unroll
  for (int t = 0; t < 8; t += 2) {
    double2 v = *(const double2*)&qrow[ll * 8 + t];
    qd[t] = v.x; qd[t + 1] = v.y;
  }

  const int* tix = topidx + (size_t)row_global * CAND2 + w * 16;
  int cis[8];
  #pragma unroll
  for (int j = 0; j < 8; ++j) cis[j] = tix[2 * j + c2];
  float4 cva[8], cvb[8];
  #pragma unroll
  for (int j = 0; j < 8; ++j) {
    const int ci = cis[j];
    const float* cp = (ci < C_) ? ctx + ((size_t)b * C_ + ci) * D_
                                : mem + ((size_t)b * K_ + (ci - C_)) * D_;
    cva[j] = *(const float4*)&cp[ll * 8];
    cvb[j] = *(const float4*)&cp[ll * 8 + 4];
  }

  #pragma unroll
  for (int j = 0; j < 8; ++j) {
    double a0 = 0.0, a1 = 0.0, df;
    df = qd[0] - (double)cva[j].x; a0 = fma(df, df, a0);
    df = qd[1] - (double)cva[j].y; a1 = fma(df, df, a1);
    df = qd[2] - (double)cva[j].z; a0 = fma(df, df, a0);
    df = qd[3] - (double)cva[j].w; a1 = fma(df, df, a1);
    df = qd[4] - (double)cvb[j].x; a0 = fma(df, df, a0);
    df = qd[5] - (double)cvb[j].y; a1 = fma(df, df, a1);
    df = qd[6] - (double)cvb[j].z; a0 = fma(df, df, a0);
    df = qd[7] - (double)cvb[j].w; a1 = fma(df, df, a1);
    double acc = a0 + a1;
    #pragma unroll
    for (int off = 16; off > 0; off >>= 1) acc += __shfl_down(acc, off, 32);
    if (ll == 0) { d2s[w * 16 + 2 * j + c2] = acc; ids_s[w * 16 + 2 * j + c2] = cis[j]; }
  }
  __syncthreads();

  if (w == 0) {
    double d2 = d2s[lane];
    int    ci = ids_s[lane];
    #pragma unroll
    for (int k = 2; k <= 64; k <<= 1) {
      #pragma unroll
      for (int j2 = k >> 1; j2 > 0; j2 >>= 1) {
        const double od2 = __shfl_xor(d2, j2);
        const int    oci = __shfl_xor(ci, j2);
        const bool up = ((lane & k) == 0);
        const bool less = (d2 < od2) || (d2 == od2 && ci < oci);
        const bool keep_min = (((lane & j2) == 0) == up);
        const bool take = keep_min ? !less : less;
        if (take) { d2 = od2; ci = oci; }
      }
    }
    if (lane < TOPN) {
      const size_t obase = (size_t)row_global * TOPN;
      out[obase + lane] = (float)sqrt(d2 < 0.0 ? 0.0 : d2);
      out[(size_t)B_ * S_ * TOPN + obase + lane] = (float)ci;
    }
  }
}

extern "C" void kernel_launch(void* const* d_in, const int* in_sizes, int n_in,
                              void* d_out, int out_size, void* d_ws, size_t ws_size,
                              hipStream_t stream) {
  const float* q    = (const float*)d_in[0];
  const float* ctx  = (const float*)d_in[1];
  const float* mem  = (const float*)d_in[2];
  const float* W    = (const float*)d_in[3];
  const float* bias = (const float*)d_in[4];
  float* out = (float*)d_out;

  double* qp64 = (double*)d_ws;                                             // 8 MB
  __hip_bfloat16* qpb = (__hip_bfloat16*)(qp64 + (size_t)B_ * S_ * D_);     // 2 MB
  unsigned short* candb = (unsigned short*)(qpb + (size_t)B_ * S_ * D_);    // 8.5 MB
  float* cn    = (float*)(candb + (size_t)B_ * NC * D_);                    // 66.5 KB
  int*   topidx = (int*)(cn + (size_t)B_ * NC);                             // 1 MB

  proj64_kernel<<<dim3(64, 4), 256, 0, stream>>>(q, W, bias, qp64, qpb);
  cvt_norm_kernel<<<(B_ * C_ * 64) / 256, 256, 0, stream>>>(ctx, candb, cn, 12, 0, 0);
  cvt_norm_kernel<<<(B_ * K_ * 64) / 256, 256, 0, stream>>>(mem, candb, cn, 6, C_, C_);
  dist_topk_kernel<<<1024, 256, 0, stream>>>(qpb, candb, cn, topidx);
  refine_kernel<<<B_ * S_, 256, 0, stream>>>(qp64, ctx, mem, topidx, out);
}

// Round 10
// 93.080 us; speedup vs baseline: 8.7222x; 1.1853x over previous
//
#include <hip/hip_runtime.h>
#include <hip/hip_bf16.h>
#include <cfloat>
#include <cmath>

#define B_ 4
#define S_ 1024
#define C_ 4096
#define K_ 64
#define D_ 256
#define NC 4160   // C_ + K_  (= 260 groups of 16)
#define TOPN 16
#define CAND2 64  // 4 splits x 16 keys; refine narrows to 32 by key

typedef __attribute__((ext_vector_type(8))) short short8;
typedef __attribute__((ext_vector_type(4))) float f32x4;

// ---------------- projection (fp64 accumulate) + bf16 copy of qp ----------------
__global__ __launch_bounds__(256) void proj64_kernel(
    const float* __restrict__ q, const float* __restrict__ W,
    const float* __restrict__ bias, double* __restrict__ qp64,
    __hip_bfloat16* __restrict__ qpb)
{
  __shared__ alignas(16) float As[64][36];
  __shared__ alignas(16) float Ws[64][36];
  const int tid = threadIdx.x;
  const int m0 = blockIdx.x * 64;
  const int n0 = blockIdx.y * 64;
  const int tx = tid & 15;
  const int ty = tid >> 4;
  const int lr = tid >> 3;
  const int lk = (tid & 7) * 4;
  double acc[4][4] = {};
  for (int k0 = 0; k0 < D_; k0 += 32) {
    __syncthreads();
    {
      float4 a0 = *(const float4*)&q[(size_t)(m0 + lr) * D_ + k0 + lk];
      float4 a1 = *(const float4*)&q[(size_t)(m0 + lr + 32) * D_ + k0 + lk];
      *(float4*)&As[lr][lk] = a0;
      *(float4*)&As[lr + 32][lk] = a1;
      float4 w0 = *(const float4*)&W[(size_t)(n0 + lr) * D_ + k0 + lk];
      float4 w1 = *(const float4*)&W[(size_t)(n0 + lr + 32) * D_ + k0 + lk];
      *(float4*)&Ws[lr][lk] = w0;
      *(float4*)&Ws[lr + 32][lk] = w1;
    }
    __syncthreads();
    #pragma unroll
    for (int kk = 0; kk < 32; kk += 4) {
      float4 av[4], wv[4];
      #pragma unroll
      for (int i = 0; i < 4; ++i) av[i] = *(const float4*)&As[ty * 4 + i][kk];
      #pragma unroll
      for (int j = 0; j < 4; ++j) wv[j] = *(const float4*)&Ws[tx + 16 * j][kk];
      #pragma unroll
      for (int i = 0; i < 4; ++i)
        #pragma unroll
        for (int j = 0; j < 4; ++j) {
          acc[i][j] = fma((double)av[i].x, (double)wv[j].x, acc[i][j]);
          acc[i][j] = fma((double)av[i].y, (double)wv[j].y, acc[i][j]);
          acc[i][j] = fma((double)av[i].z, (double)wv[j].z, acc[i][j]);
          acc[i][j] = fma((double)av[i].w, (double)wv[j].w, acc[i][j]);
        }
    }
  }
  #pragma unroll
  for (int i = 0; i < 4; ++i) {
    const int m = m0 + ty * 4 + i;
    #pragma unroll
    for (int j = 0; j < 4; ++j) {
      const int n = n0 + tx + 16 * j;
      const double v = acc[i][j] + (double)bias[n];
      qp64[(size_t)m * D_ + n] = v;
      qpb[(size_t)m * D_ + n] = __float2bfloat16((float)v);
    }
  }
}

// ---------------- fused fp32->bf16 cast (FRAGMENT-MAJOR layout) + row norms ----------------
__global__ __launch_bounds__(256) void cvt_norm_kernel(
    const float* __restrict__ src, unsigned short* __restrict__ dst,
    float* __restrict__ normp, int log2_rows_per_batch, int dst_row_base, int norm_base)
{
  const int e4 = blockIdx.x * 256 + threadIdx.x;   // float4 index
  const int row = e4 >> 6;
  const int b = row >> log2_rows_per_batch;
  const int r = row & ((1 << log2_rows_per_batch) - 1);
  const int k4 = e4 & 63;
  const float4 v = ((const float4*)src)[e4];
  const int R = dst_row_base + r;
  const int g = R >> 4, l15 = R & 15;
  const int k = k4 * 4;
  const int s = k >> 5, lg = (k & 31) >> 3, i = k & 7;
  unsigned short* d = dst + (size_t)b * (NC * D_) +
                      (size_t)g * 4096 + s * 512 + lg * 128 + l15 * 8 + i;
  ushort4 o;
  __hip_bfloat16 h0 = __float2bfloat16(v.x); o.x = *(unsigned short*)&h0;
  __hip_bfloat16 h1 = __float2bfloat16(v.y); o.y = *(unsigned short*)&h1;
  __hip_bfloat16 h2 = __float2bfloat16(v.z); o.z = *(unsigned short*)&h2;
  __hip_bfloat16 h3 = __float2bfloat16(v.w); o.w = *(unsigned short*)&h3;
  *(ushort4*)d = o;
  float sacc = v.x * v.x + v.y * v.y + v.z * v.z + v.w * v.w;
  #pragma unroll
  for (int off = 32; off > 0; off >>= 1) sacc += __shfl_down(sacc, off);
  if ((threadIdx.x & 63) == 0) normp[b * NC + norm_base + r] = sacc;
}

// ---------------- pass 1: MFMA + quad-filtered min/max-bubble top-16 keys ----------------
#define INSERT_CANDS(ACC, CBASE)                                              \
  {                                                                           \
    const float4 cn4 = *(const float4*)&cnb[(CBASE) + lg * 4];                \
    unsigned kk[4];                                                           \
    _Pragma("unroll")                                                         \
    for (int r = 0; r < 4; ++r) {                                             \
      const float d2v = fmaf(-2.0f, (ACC)[r], ((const float*)&cn4)[r]);       \
      kk[r] = (__float_as_uint(d2v) & 0xFFFFE000u)                            \
              | (unsigned)((CBASE) + lg * 4 + r);                             \
    }                                                                         \
    const unsigned km01 = kk[0] < kk[1] ? kk[0] : kk[1];                      \
    const unsigned km23 = kk[2] < kk[3] ? kk[2] : kk[3];                      \
    const unsigned km = km01 < km23 ? km01 : km23;                            \
    if (km < ld[15]) {                                                        \
      _Pragma("unroll")                                                       \
      for (int r = 0; r < 4; ++r) {                                           \
        if (kk[r] < ld[15]) {                                                 \
          ld[15] = kk[r];                                                     \
          _Pragma("unroll")                                                   \
          for (int i = 15; i > 0; --i) {                                      \
            const unsigned a = ld[i - 1], c = ld[i];                          \
            ld[i - 1] = a < c ? a : c;                                        \
            ld[i]     = a < c ? c : a;                                        \
          }                                                                   \
        }                                                                     \
      }                                                                       \
    }                                                                         \
  }

// 4-accumulator MFMA chain: 2-deep dependency
#define MFMA_CHAIN(ACC, FRAGS)                                                \
  f32x4 ACC;                                                                  \
  {                                                                           \
    f32x4 c0_ = {0.f,0.f,0.f,0.f}, c1_ = {0.f,0.f,0.f,0.f};                   \
    f32x4 c2_ = {0.f,0.f,0.f,0.f}, c3_ = {0.f,0.f,0.f,0.f};                   \
    c0_ = __builtin_amdgcn_mfma_f32_16x16x32_bf16((FRAGS)[0], bfr[0], c0_, 0, 0, 0); \
    c1_ = __builtin_amdgcn_mfma_f32_16x16x32_bf16((FRAGS)[1], bfr[1], c1_, 0, 0, 0); \
    c2_ = __builtin_amdgcn_mfma_f32_16x16x32_bf16((FRAGS)[2], bfr[2], c2_, 0, 0, 0); \
    c3_ = __builtin_amdgcn_mfma_f32_16x16x32_bf16((FRAGS)[3], bfr[3], c3_, 0, 0, 0); \
    c0_ = __builtin_amdgcn_mfma_f32_16x16x32_bf16((FRAGS)[4], bfr[4], c0_, 0, 0, 0); \
    c1_ = __builtin_amdgcn_mfma_f32_16x16x32_bf16((FRAGS)[5], bfr[5], c1_, 0, 0, 0); \
    c2_ = __builtin_amdgcn_mfma_f32_16x16x32_bf16((FRAGS)[6], bfr[6], c2_, 0, 0, 0); \
    c3_ = __builtin_amdgcn_mfma_f32_16x16x32_bf16((FRAGS)[7], bfr[7], c3_, 0, 0, 0); \
    ACC = (c0_ + c1_) + (c2_ + c3_);                                          \
  }

__global__ __launch_bounds__(256) void dist_topk_kernel(
    const __hip_bfloat16* __restrict__ qpb, const unsigned short* __restrict__ candb,
    const float* __restrict__ cn, unsigned* __restrict__ topidx)
{
  const int b = blockIdx.x & 3;
  const int split = (blockIdx.x >> 2) & 3;
  const int rt = blockIdx.x >> 4;          // 0..63
  const int row0 = rt * 16;
  const int tid = threadIdx.x;
  const int w = tid >> 6;          // wave 0..3
  const int lane = tid & 63;
  const int l15 = lane & 15;
  const int lg = lane >> 4;        // 0..3

  __shared__ unsigned md[16][16][17];   // [row][list][entry], pad 17

  short8 bfr[8];
  {
    const short* qrow = (const short*)qpb + ((size_t)(b * S_ + row0 + l15)) * D_ + lg * 8;
    #pragma unroll
    for (int s = 0; s < 8; ++s) bfr[s] = *(const short8*)(qrow + s * 32);
  }

  const float* cnb = cn + b * NC;
  const short* cbp = (const short*)candb + (size_t)b * NC * D_ + lg * 128 + l15 * 8;

  unsigned ld[16];
  #pragma unroll
  for (int i = 0; i < TOPN; ++i) ld[i] = 0xFFFFFFFFu;

  const int gbase = split + 4 * w;     // group id; candidate base = g*16
  const int gtail = 256 + split;

  short8 aA[8], aB[8];
  #pragma unroll
  for (int s = 0; s < 8; ++s)
    aA[s] = *(const short8*)(cbp + (size_t)gbase * 4096 + s * 512);

  for (int j = 0; j < 8; ++j) {
    const int gA = gbase + 32 * j;
    const int gB = gA + 16;
    #pragma unroll
    for (int s = 0; s < 8; ++s)
      aB[s] = *(const short8*)(cbp + (size_t)gB * 4096 + s * 512);

    MFMA_CHAIN(acc, aA);

    if (j < 7) {
      #pragma unroll
      for (int s = 0; s < 8; ++s)
        aA[s] = *(const short8*)(cbp + (size_t)(gA + 32) * 4096 + s * 512);
    } else if (w == 3) {
      #pragma unroll
      for (int s = 0; s < 8; ++s)
        aA[s] = *(const short8*)(cbp + (size_t)gtail * 4096 + s * 512);
    }

    MFMA_CHAIN(acc2, aB);

    INSERT_CANDS(acc, gA * 16);
    INSERT_CANDS(acc2, gB * 16);
  }
  if (w == 3) {   // memory-candidate group
    MFMA_CHAIN(acc, aA);
    INSERT_CANDS(acc, gtail * 16);
  }

  const int lid = w * 4 + lg;
  #pragma unroll
  for (int i = 0; i < TOPN; ++i) md[l15][lid][i] = ld[i];
  __syncthreads();

  {
    const int g = lane >> 4;          // row-in-wave 0..3
    const int h = l15;                // list id
    const int row = w * 4 + g;
    int ptr = 0;
    unsigned cur = md[row][h][0];
    unsigned mykey = 0xFFFFFFFFu;     // lane h captures the h-th smallest
    #pragma unroll
    for (int it = 0; it < TOPN; ++it) {
      unsigned m = cur;
      #pragma unroll
      for (int off = 8; off > 0; off >>= 1) {
        const unsigned o = __shfl_xor(m, off, 16);
        m = (o < m) ? o : m;
      }
      if (h == it) mykey = m;
      if (cur == m) {                 // unique winner advances its head
        ++ptr;
        cur = (ptr < TOPN) ? md[row][h][ptr] : 0xFFFFFFFFu;
      }
    }
    // store the FULL packed key (idx in low 13 bits) — refine sorts by key
    unsigned* dst = topidx + ((size_t)(b * S_ + row0 + row)) * CAND2 + split * TOPN;
    dst[h] = mykey;
  }
}

// ---------------- pass 2: key-presort -> gather 32 -> fp64 refine -> bitonic top-16 ----------------
__global__ __launch_bounds__(256) void refine_kernel(
    const double* __restrict__ qp64, const float* __restrict__ ctx,
    const float* __restrict__ mem, const unsigned* __restrict__ topidx,
    float* __restrict__ out)
{
  const int row_global = blockIdx.x;
  const int tid = threadIdx.x;
  const int w = tid >> 6;         // wave 0..3: candidates [w*8, w*8+8)
  const int lane = tid & 63;
  const int c2 = lane >> 5;       // which cand of the pair
  const int ll = lane & 31;       // dim slice: [ll*8, ll*8+8)
  const int b = row_global >> 10;

  __shared__ int    sel[32];
  __shared__ double d2s[64];
  __shared__ int    ids_s[64];

  // wave 0: bitonic-sort the 64 packed keys, keep 32 smallest (superset of true top-16)
  if (w == 0) {
    unsigned key = topidx[(size_t)row_global * CAND2 + lane];
    #pragma unroll
    for (int k = 2; k <= 64; k <<= 1) {
      #pragma unroll
      for (int j2 = k >> 1; j2 > 0; j2 >>= 1) {
        const unsigned o = __shfl_xor(key, j2);
        const bool up = ((lane & k) == 0);
        const bool keep_min = (((lane & j2) == 0) == up);
        const bool less = key < o;
        if (keep_min ? !less : less) key = o;
      }
    }
    if (lane < 32) sel[lane] = (int)(key & 0x1FFFu);
  }
  if (w == 1 && lane < 32) { d2s[32 + lane] = DBL_MAX; ids_s[32 + lane] = 0x7fffffff; }
  __syncthreads();

  const double* qrow = qp64 + (size_t)row_global * D_;
  double qd[8];
  #pragma unroll
  for (int t = 0; t < 8; t += 2) {
    double2 v = *(const double2*)&qrow[ll * 8 + t];
    qd[t] = v.x; qd[t + 1] = v.y;
  }

  // wave w handles sel[w*8 .. w*8+8): 4 pair-iterations, preloaded
  int cis[4]; float4 cva[4], cvb[4];
  #pragma unroll
  for (int j = 0; j < 4; ++j) cis[j] = sel[w * 8 + 2 * j + c2];
  #pragma unroll
  for (int j = 0; j < 4; ++j) {
    const int ci = cis[j];
    const float* cp = (ci < C_) ? ctx + ((size_t)b * C_ + ci) * D_
                                : mem + ((size_t)b * K_ + (ci - C_)) * D_;
    cva[j] = *(const float4*)&cp[ll * 8];
    cvb[j] = *(const float4*)&cp[ll * 8 + 4];
  }

  #pragma unroll
  for (int j = 0; j < 4; ++j) {
    double a0 = 0.0, a1 = 0.0, df;
    df = qd[0] - (double)cva[j].x; a0 = fma(df, df, a0);
    df = qd[1] - (double)cva[j].y; a1 = fma(df, df, a1);
    df = qd[2] - (double)cva[j].z; a0 = fma(df, df, a0);
    df = qd[3] - (double)cva[j].w; a1 = fma(df, df, a1);
    df = qd[4] - (double)cvb[j].x; a0 = fma(df, df, a0);
    df = qd[5] - (double)cvb[j].y; a1 = fma(df, df, a1);
    df = qd[6] - (double)cvb[j].z; a0 = fma(df, df, a0);
    df = qd[7] - (double)cvb[j].w; a1 = fma(df, df, a1);
    double acc = a0 + a1;
    #pragma unroll
    for (int off = 16; off > 0; off >>= 1) acc += __shfl_down(acc, off, 32);
    if (ll == 0) { d2s[w * 8 + 2 * j + c2] = acc; ids_s[w * 8 + 2 * j + c2] = cis[j]; }
  }
  __syncthreads();

  // wave 0: exact bitonic sort of 32 real + 32 pad (d2, idx) pairs
  if (w == 0) {
    double d2 = d2s[lane];
    int    ci = ids_s[lane];
    #pragma unroll
    for (int k = 2; k <= 64; k <<= 1) {
      #pragma unroll
      for (int j2 = k >> 1; j2 > 0; j2 >>= 1) {
        const double od2 = __shfl_xor(d2, j2);
        const int    oci = __shfl_xor(ci, j2);
        const bool up = ((lane & k) == 0);
        const bool less = (d2 < od2) || (d2 == od2 && ci < oci);
        const bool keep_min = (((lane & j2) == 0) == up);
        const bool take = keep_min ? !less : less;
        if (take) { d2 = od2; ci = oci; }
      }
    }
    if (lane < TOPN) {
      const size_t obase = (size_t)row_global * TOPN;
      out[obase + lane] = (float)sqrt(d2 < 0.0 ? 0.0 : d2);
      out[(size_t)B_ * S_ * TOPN + obase + lane] = (float)ci;
    }
  }
}

extern "C" void kernel_launch(void* const* d_in, const int* in_sizes, int n_in,
                              void* d_out, int out_size, void* d_ws, size_t ws_size,
                              hipStream_t stream) {
  const float* q    = (const float*)d_in[0];
  const float* ctx  = (const float*)d_in[1];
  const float* mem  = (const float*)d_in[2];
  const float* W    = (const float*)d_in[3];
  const float* bias = (const float*)d_in[4];
  float* out = (float*)d_out;

  double* qp64 = (double*)d_ws;                                             // 8 MB
  __hip_bfloat16* qpb = (__hip_bfloat16*)(qp64 + (size_t)B_ * S_ * D_);     // 2 MB
  unsigned short* candb = (unsigned short*)(qpb + (size_t)B_ * S_ * D_);    // 8.5 MB
  float* cn    = (float*)(candb + (size_t)B_ * NC * D_);                    // 66.5 KB
  unsigned* topidx = (unsigned*)(cn + (size_t)B_ * NC);                     // 1 MB

  proj64_kernel<<<dim3(64, 4), 256, 0, stream>>>(q, W, bias, qp64, qpb);
  cvt_norm_kernel<<<(B_ * C_ * 64) / 256, 256, 0, stream>>>(ctx, candb, cn, 12, 0, 0);
  cvt_norm_kernel<<<(B_ * K_ * 64) / 256, 256, 0, stream>>>(mem, candb, cn, 6, C_, C_);
  dist_topk_kernel<<<1024, 256, 0, stream>>>(qpb, candb, cn, topidx);
  refine_kernel<<<B_ * S_, 256, 0, stream>>>(qp64, ctx, mem, topidx, out);
}

// Round 11
// 91.646 us; speedup vs baseline: 8.8587x; 1.0156x over previous
//
#include <hip/hip_runtime.h>
#include <hip/hip_bf16.h>
#include <cfloat>
#include <cmath>

#define B_ 4
#define S_ 1024
#define C_ 4096
#define K_ 64
#define D_ 256
#define NC 4160   // C_ + K_  (= 260 groups of 16)
#define TOPN 16
#define CAND2 64  // 4 splits x 16 keys; refine narrows to 32 by key

typedef __attribute__((ext_vector_type(8))) short short8;
typedef __attribute__((ext_vector_type(4))) float f32x4;

// ---------------- projection (fp64 accumulate) + bf16 copy of qp ----------------
__global__ __launch_bounds__(256) void proj64_kernel(
    const float* __restrict__ q, const float* __restrict__ W,
    const float* __restrict__ bias, double* __restrict__ qp64,
    __hip_bfloat16* __restrict__ qpb)
{
  __shared__ alignas(16) float As[64][36];
  __shared__ alignas(16) float Ws[64][36];
  const int tid = threadIdx.x;
  const int m0 = blockIdx.x * 64;
  const int n0 = blockIdx.y * 64;
  const int tx = tid & 15;
  const int ty = tid >> 4;
  const int lr = tid >> 3;
  const int lk = (tid & 7) * 4;
  double acc[4][4] = {};
  for (int k0 = 0; k0 < D_; k0 += 32) {
    __syncthreads();
    {
      float4 a0 = *(const float4*)&q[(size_t)(m0 + lr) * D_ + k0 + lk];
      float4 a1 = *(const float4*)&q[(size_t)(m0 + lr + 32) * D_ + k0 + lk];
      *(float4*)&As[lr][lk] = a0;
      *(float4*)&As[lr + 32][lk] = a1;
      float4 w0 = *(const float4*)&W[(size_t)(n0 + lr) * D_ + k0 + lk];
      float4 w1 = *(const float4*)&W[(size_t)(n0 + lr + 32) * D_ + k0 + lk];
      *(float4*)&Ws[lr][lk] = w0;
      *(float4*)&Ws[lr + 32][lk] = w1;
    }
    __syncthreads();
    #pragma unroll
    for (int kk = 0; kk < 32; kk += 4) {
      float4 av[4], wv[4];
      #pragma unroll
      for (int i = 0; i < 4; ++i) av[i] = *(const float4*)&As[ty * 4 + i][kk];
      #pragma unroll
      for (int j = 0; j < 4; ++j) wv[j] = *(const float4*)&Ws[tx + 16 * j][kk];
      #pragma unroll
      for (int i = 0; i < 4; ++i)
        #pragma unroll
        for (int j = 0; j < 4; ++j) {
          acc[i][j] = fma((double)av[i].x, (double)wv[j].x, acc[i][j]);
          acc[i][j] = fma((double)av[i].y, (double)wv[j].y, acc[i][j]);
          acc[i][j] = fma((double)av[i].z, (double)wv[j].z, acc[i][j]);
          acc[i][j] = fma((double)av[i].w, (double)wv[j].w, acc[i][j]);
        }
    }
  }
  #pragma unroll
  for (int i = 0; i < 4; ++i) {
    const int m = m0 + ty * 4 + i;
    #pragma unroll
    for (int j = 0; j < 4; ++j) {
      const int n = n0 + tx + 16 * j;
      const double v = acc[i][j] + (double)bias[n];
      qp64[(size_t)m * D_ + n] = v;
      qpb[(size_t)m * D_ + n] = __float2bfloat16((float)v);
    }
  }
}

// ---------------- fused fp32->bf16 cast (FRAGMENT-MAJOR layout) + row norms ----------------
__global__ __launch_bounds__(256) void cvt_norm_kernel(
    const float* __restrict__ src, unsigned short* __restrict__ dst,
    float* __restrict__ normp, int log2_rows_per_batch, int dst_row_base, int norm_base)
{
  const int e4 = blockIdx.x * 256 + threadIdx.x;   // float4 index
  const int row = e4 >> 6;
  const int b = row >> log2_rows_per_batch;
  const int r = row & ((1 << log2_rows_per_batch) - 1);
  const int k4 = e4 & 63;
  const float4 v = ((const float4*)src)[e4];
  const int R = dst_row_base + r;
  const int g = R >> 4, l15 = R & 15;
  const int k = k4 * 4;
  const int s = k >> 5, lg = (k & 31) >> 3, i = k & 7;
  unsigned short* d = dst + (size_t)b * (NC * D_) +
                      (size_t)g * 4096 + s * 512 + lg * 128 + l15 * 8 + i;
  ushort4 o;
  __hip_bfloat16 h0 = __float2bfloat16(v.x); o.x = *(unsigned short*)&h0;
  __hip_bfloat16 h1 = __float2bfloat16(v.y); o.y = *(unsigned short*)&h1;
  __hip_bfloat16 h2 = __float2bfloat16(v.z); o.z = *(unsigned short*)&h2;
  __hip_bfloat16 h3 = __float2bfloat16(v.w); o.w = *(unsigned short*)&h3;
  *(ushort4*)d = o;
  float sacc = v.x * v.x + v.y * v.y + v.z * v.z + v.w * v.w;
  #pragma unroll
  for (int off = 32; off > 0; off >>= 1) sacc += __shfl_down(sacc, off);
  if ((threadIdx.x & 63) == 0) normp[b * NC + norm_base + r] = sacc;
}

// ---------------- pass 1: MFMA + branchless sort4 + order-statistic list merge ----------------
#define UMIN(a, b) ((a) < (b) ? (a) : (b))
#define UMAX(a, b) ((a) < (b) ? (b) : (a))

// Merge sorted ld[16] with 4 new keys: new ld = smallest 16 of the 20.
// Identity: new[i] = min over j of max(ld[i-j], B[j-1])  (B = sorted quad).
// Branchless, depth ~5 — replaces the 15-level serial bubble insert.
#define INSERT_CANDS(ACC, CBASE)                                              \
  {                                                                           \
    const float4 cn4 = *(const float4*)&cnb[(CBASE) + lg * 4];                \
    unsigned k0, k1, k2, k3;                                                  \
    {                                                                         \
      unsigned kk[4];                                                         \
      _Pragma("unroll")                                                       \
      for (int r = 0; r < 4; ++r) {                                           \
        const float d2v = fmaf(-2.0f, (ACC)[r], ((const float*)&cn4)[r]);     \
        kk[r] = (__float_as_uint(d2v) & 0xFFFFE000u)                          \
                | (unsigned)((CBASE) + lg * 4 + r);                           \
      }                                                                       \
      unsigned t;                                                             \
      t = UMIN(kk[0], kk[1]); kk[1] = UMAX(kk[0], kk[1]); kk[0] = t;          \
      t = UMIN(kk[2], kk[3]); kk[3] = UMAX(kk[2], kk[3]); kk[2] = t;          \
      t = UMIN(kk[0], kk[2]); kk[2] = UMAX(kk[0], kk[2]); kk[0] = t;          \
      t = UMIN(kk[1], kk[3]); kk[3] = UMAX(kk[1], kk[3]); kk[1] = t;          \
      t = UMIN(kk[1], kk[2]); kk[2] = UMAX(kk[1], kk[2]); kk[1] = t;          \
      k0 = kk[0]; k1 = kk[1]; k2 = kk[2]; k3 = kk[3];                         \
    }                                                                         \
    unsigned nl[16];                                                          \
    nl[0] = UMIN(ld[0], k0);                                                  \
    nl[1] = UMIN(UMIN(ld[1], UMAX(ld[0], k0)), k1);                           \
    nl[2] = UMIN(UMIN(ld[2], UMAX(ld[1], k0)),                                \
                 UMIN(UMAX(ld[0], k1), k2));                                  \
    nl[3] = UMIN(UMIN(UMIN(ld[3], UMAX(ld[2], k0)),                           \
                      UMIN(UMAX(ld[1], k1), UMAX(ld[0], k2))), k3);           \
    _Pragma("unroll")                                                         \
    for (int i = 4; i < 16; ++i) {                                            \
      nl[i] = UMIN(UMIN(UMIN(ld[i], UMAX(ld[i - 1], k0)),                     \
                        UMIN(UMAX(ld[i - 2], k1), UMAX(ld[i - 3], k2))),      \
                   UMAX(ld[i - 4], k3));                                      \
    }                                                                         \
    _Pragma("unroll")                                                         \
    for (int i = 0; i < 16; ++i) ld[i] = nl[i];                               \
  }

// 4-accumulator MFMA chain: 2-deep dependency
#define MFMA_CHAIN(ACC, FRAGS)                                                \
  f32x4 ACC;                                                                  \
  {                                                                           \
    f32x4 c0_ = {0.f,0.f,0.f,0.f}, c1_ = {0.f,0.f,0.f,0.f};                   \
    f32x4 c2_ = {0.f,0.f,0.f,0.f}, c3_ = {0.f,0.f,0.f,0.f};                   \
    c0_ = __builtin_amdgcn_mfma_f32_16x16x32_bf16((FRAGS)[0], bfr[0], c0_, 0, 0, 0); \
    c1_ = __builtin_amdgcn_mfma_f32_16x16x32_bf16((FRAGS)[1], bfr[1], c1_, 0, 0, 0); \
    c2_ = __builtin_amdgcn_mfma_f32_16x16x32_bf16((FRAGS)[2], bfr[2], c2_, 0, 0, 0); \
    c3_ = __builtin_amdgcn_mfma_f32_16x16x32_bf16((FRAGS)[3], bfr[3], c3_, 0, 0, 0); \
    c0_ = __builtin_amdgcn_mfma_f32_16x16x32_bf16((FRAGS)[4], bfr[4], c0_, 0, 0, 0); \
    c1_ = __builtin_amdgcn_mfma_f32_16x16x32_bf16((FRAGS)[5], bfr[5], c1_, 0, 0, 0); \
    c2_ = __builtin_amdgcn_mfma_f32_16x16x32_bf16((FRAGS)[6], bfr[6], c2_, 0, 0, 0); \
    c3_ = __builtin_amdgcn_mfma_f32_16x16x32_bf16((FRAGS)[7], bfr[7], c3_, 0, 0, 0); \
    ACC = (c0_ + c1_) + (c2_ + c3_);                                          \
  }

__global__ __launch_bounds__(256) void dist_topk_kernel(
    const __hip_bfloat16* __restrict__ qpb, const unsigned short* __restrict__ candb,
    const float* __restrict__ cn, unsigned* __restrict__ topidx)
{
  const int b = blockIdx.x & 3;
  const int split = (blockIdx.x >> 2) & 3;
  const int rt = blockIdx.x >> 4;          // 0..63
  const int row0 = rt * 16;
  const int tid = threadIdx.x;
  const int w = tid >> 6;          // wave 0..3
  const int lane = tid & 63;
  const int l15 = lane & 15;
  const int lg = lane >> 4;        // 0..3

  __shared__ unsigned md[16][16][17];   // [row][list][entry], pad 17

  short8 bfr[8];
  {
    const short* qrow = (const short*)qpb + ((size_t)(b * S_ + row0 + l15)) * D_ + lg * 8;
    #pragma unroll
    for (int s = 0; s < 8; ++s) bfr[s] = *(const short8*)(qrow + s * 32);
  }

  const float* cnb = cn + b * NC;
  const short* cbp = (const short*)candb + (size_t)b * NC * D_ + lg * 128 + l15 * 8;

  unsigned ld[16];
  #pragma unroll
  for (int i = 0; i < TOPN; ++i) ld[i] = 0xFFFFFFFFu;

  const int gbase = split + 4 * w;     // group id; candidate base = g*16
  const int gtail = 256 + split;

  short8 aA[8], aB[8];
  #pragma unroll
  for (int s = 0; s < 8; ++s)
    aA[s] = *(const short8*)(cbp + (size_t)gbase * 4096 + s * 512);

  for (int j = 0; j < 8; ++j) {
    const int gA = gbase + 32 * j;
    const int gB = gA + 16;
    #pragma unroll
    for (int s = 0; s < 8; ++s)
      aB[s] = *(const short8*)(cbp + (size_t)gB * 4096 + s * 512);

    MFMA_CHAIN(acc, aA);

    if (j < 7) {
      #pragma unroll
      for (int s = 0; s < 8; ++s)
        aA[s] = *(const short8*)(cbp + (size_t)(gA + 32) * 4096 + s * 512);
    } else if (w == 3) {
      #pragma unroll
      for (int s = 0; s < 8; ++s)
        aA[s] = *(const short8*)(cbp + (size_t)gtail * 4096 + s * 512);
    }

    MFMA_CHAIN(acc2, aB);

    INSERT_CANDS(acc, gA * 16);
    INSERT_CANDS(acc2, gB * 16);
  }
  if (w == 3) {   // memory-candidate group
    MFMA_CHAIN(acc, aA);
    INSERT_CANDS(acc, gtail * 16);
  }

  const int lid = w * 4 + lg;
  #pragma unroll
  for (int i = 0; i < TOPN; ++i) md[l15][lid][i] = ld[i];
  __syncthreads();

  {
    const int g = lane >> 4;          // row-in-wave 0..3
    const int h = l15;                // list id
    const int row = w * 4 + g;
    int ptr = 0;
    unsigned cur = md[row][h][0];
    unsigned mykey = 0xFFFFFFFFu;     // lane h captures the h-th smallest
    #pragma unroll
    for (int it = 0; it < TOPN; ++it) {
      unsigned m = cur;
      #pragma unroll
      for (int off = 8; off > 0; off >>= 1) {
        const unsigned o = __shfl_xor(m, off, 16);
        m = (o < m) ? o : m;
      }
      if (h == it) mykey = m;
      if (cur == m) {                 // unique winner advances its head
        ++ptr;
        cur = (ptr < TOPN) ? md[row][h][ptr] : 0xFFFFFFFFu;
      }
    }
    // store the FULL packed key (idx in low 13 bits) — refine sorts by key
    unsigned* dst = topidx + ((size_t)(b * S_ + row0 + row)) * CAND2 + split * TOPN;
    dst[h] = mykey;
  }
}

// ---------------- pass 2: key-presort -> gather 32 -> fp64 refine -> bitonic top-16 ----------------
__global__ __launch_bounds__(256) void refine_kernel(
    const double* __restrict__ qp64, const float* __restrict__ ctx,
    const float* __restrict__ mem, const unsigned* __restrict__ topidx,
    float* __restrict__ out)
{
  const int row_global = blockIdx.x;
  const int tid = threadIdx.x;
  const int w = tid >> 6;         // wave 0..3: candidates [w*8, w*8+8)
  const int lane = tid & 63;
  const int c2 = lane >> 5;       // which cand of the pair
  const int ll = lane & 31;       // dim slice: [ll*8, ll*8+8)
  const int b = row_global >> 10;

  __shared__ int    sel[32];
  __shared__ double d2s[64];
  __shared__ int    ids_s[64];

  // wave 0: bitonic-sort the 64 packed keys, keep 32 smallest (superset of true top-16)
  if (w == 0) {
    unsigned key = topidx[(size_t)row_global * CAND2 + lane];
    #pragma unroll
    for (int k = 2; k <= 64; k <<= 1) {
      #pragma unroll
      for (int j2 = k >> 1; j2 > 0; j2 >>= 1) {
        const unsigned o = __shfl_xor(key, j2);
        const bool up = ((lane & k) == 0);
        const bool keep_min = (((lane & j2) == 0) == up);
        const bool less = key < o;
        if (keep_min ? !less : less) key = o;
      }
    }
    if (lane < 32) sel[lane] = (int)(key & 0x1FFFu);
  }
  if (w == 1 && lane < 32) { d2s[32 + lane] = DBL_MAX; ids_s[32 + lane] = 0x7fffffff; }
  __syncthreads();

  const double* qrow = qp64 + (size_t)row_global * D_;
  double qd[8];
  #pragma unroll
  for (int t = 0; t < 8; t += 2) {
    double2 v = *(const double2*)&qrow[ll * 8 + t];
    qd[t] = v.x; qd[t + 1] = v.y;
  }

  // wave w handles sel[w*8 .. w*8+8): 4 pair-iterations, preloaded
  int cis[4]; float4 cva[4], cvb[4];
  #pragma unroll
  for (int j = 0; j < 4; ++j) cis[j] = sel[w * 8 + 2 * j + c2];
  #pragma unroll
  for (int j = 0; j < 4; ++j) {
    const int ci = cis[j];
    const float* cp = (ci < C_) ? ctx + ((size_t)b * C_ + ci) * D_
                                : mem + ((size_t)b * K_ + (ci - C_)) * D_;
    cva[j] = *(const float4*)&cp[ll * 8];
    cvb[j] = *(const float4*)&cp[ll * 8 + 4];
  }

  #pragma unroll
  for (int j = 0; j < 4; ++j) {
    double a0 = 0.0, a1 = 0.0, df;
    df = qd[0] - (double)cva[j].x; a0 = fma(df, df, a0);
    df = qd[1] - (double)cva[j].y; a1 = fma(df, df, a1);
    df = qd[2] - (double)cva[j].z; a0 = fma(df, df, a0);
    df = qd[3] - (double)cva[j].w; a1 = fma(df, df, a1);
    df = qd[4] - (double)cvb[j].x; a0 = fma(df, df, a0);
    df = qd[5] - (double)cvb[j].y; a1 = fma(df, df, a1);
    df = qd[6] - (double)cvb[j].z; a0 = fma(df, df, a0);
    df = qd[7] - (double)cvb[j].w; a1 = fma(df, df, a1);
    double acc = a0 + a1;
    #pragma unroll
    for (int off = 16; off > 0; off >>= 1) acc += __shfl_down(acc, off, 32);
    if (ll == 0) { d2s[w * 8 + 2 * j + c2] = acc; ids_s[w * 8 + 2 * j + c2] = cis[j]; }
  }
  __syncthreads();

  // wave 0: exact bitonic sort of 32 real + 32 pad (d2, idx) pairs
  if (w == 0) {
    double d2 = d2s[lane];
    int    ci = ids_s[lane];
    #pragma unroll
    for (int k = 2; k <= 64; k <<= 1) {
      #pragma unroll
      for (int j2 = k >> 1; j2 > 0; j2 >>= 1) {
        const double od2 = __shfl_xor(d2, j2);
        const int    oci = __shfl_xor(ci, j2);
        const bool up = ((lane & k) == 0);
        const bool less = (d2 < od2) || (d2 == od2 && ci < oci);
        const bool keep_min = (((lane & j2) == 0) == up);
        const bool take = keep_min ? !less : less;
        if (take) { d2 = od2; ci = oci; }
      }
    }
    if (lane < TOPN) {
      const size_t obase = (size_t)row_global * TOPN;
      out[obase + lane] = (float)sqrt(d2 < 0.0 ? 0.0 : d2);
      out[(size_t)B_ * S_ * TOPN + obase + lane] = (float)ci;
    }
  }
}

extern "C" void kernel_launch(void* const* d_in, const int* in_sizes, int n_in,
                              void* d_out, int out_size, void* d_ws, size_t ws_size,
                              hipStream_t stream) {
  const float* q    = (const float*)d_in[0];
  const float* ctx  = (const float*)d_in[1];
  const float* mem  = (const float*)d_in[2];
  const float* W    = (const float*)d_in[3];
  const float* bias = (const float*)d_in[4];
  float* out = (float*)d_out;

  double* qp64 = (double*)d_ws;                                             // 8 MB
  __hip_bfloat16* qpb = (__hip_bfloat16*)(qp64 + (size_t)B_ * S_ * D_);     // 2 MB
  unsigned short* candb = (unsigned short*)(qpb + (size_t)B_ * S_ * D_);    // 8.5 MB
  float* cn    = (float*)(candb + (size_t)B_ * NC * D_);                    // 66.5 KB
  unsigned* topidx = (unsigned*)(cn + (size_t)B_ * NC);                     // 1 MB

  proj64_kernel<<<dim3(64, 4), 256, 0, stream>>>(q, W, bias, qp64, qpb);
  cvt_norm_kernel<<<(B_ * C_ * 64) / 256, 256, 0, stream>>>(ctx, candb, cn, 12, 0, 0);
  cvt_norm_kernel<<<(B_ * K_ * 64) / 256, 256, 0, stream>>>(mem, candb, cn, 6, C_, C_);
  dist_topk_kernel<<<1024, 256, 0, stream>>>(qpb, candb, cn, topidx);
  refine_kernel<<<B_ * S_, 256, 0, stream>>>(qp64, ctx, mem, topidx, out);
}

// Round 12
// 86.322 us; speedup vs baseline: 9.4051x; 1.0617x over previous
//
#include <hip/hip_runtime.h>
#include <hip/hip_bf16.h>
#include <cfloat>
#include <cmath>

#define B_ 4
#define S_ 1024
#define C_ 4096
#define K_ 64
#define D_ 256
#define NC 4160   // C_ + K_  (= 260 groups of 16)
#define TOPN 16
#define NSPLIT 8
#define CANDK 128  // 8 splits x 16 keys; refine narrows to 32 by key

typedef __attribute__((ext_vector_type(8))) short short8;
typedef __attribute__((ext_vector_type(4))) float f32x4;

#define UMIN(a, b) ((a) < (b) ? (a) : (b))
#define UMAX(a, b) ((a) < (b) ? (b) : (a))

// ---------------- fused prep: proj64 (blocks 0..255) + cvt/norm ctx (256..4351) + mem (4352..4415) ----------------
__global__ __launch_bounds__(256) void prep_kernel(
    const float* __restrict__ q, const float* __restrict__ W,
    const float* __restrict__ bias, double* __restrict__ qp64,
    __hip_bfloat16* __restrict__ qpb,
    const float* __restrict__ ctx, const float* __restrict__ mem,
    unsigned short* __restrict__ candb, float* __restrict__ cn)
{
  __shared__ alignas(16) float As[64][36];
  __shared__ alignas(16) float Ws[64][36];
  const int blk = blockIdx.x;
  const int tid = threadIdx.x;

  if (blk < 256) {   // ---- projection ----
    const int m0 = (blk & 63) * 64;
    const int n0 = (blk >> 6) * 64;
    const int tx = tid & 15;
    const int ty = tid >> 4;
    const int lr = tid >> 3;
    const int lk = (tid & 7) * 4;
    double acc[4][4] = {};
    for (int k0 = 0; k0 < D_; k0 += 32) {
      __syncthreads();
      {
        float4 a0 = *(const float4*)&q[(size_t)(m0 + lr) * D_ + k0 + lk];
        float4 a1 = *(const float4*)&q[(size_t)(m0 + lr + 32) * D_ + k0 + lk];
        *(float4*)&As[lr][lk] = a0;
        *(float4*)&As[lr + 32][lk] = a1;
        float4 w0 = *(const float4*)&W[(size_t)(n0 + lr) * D_ + k0 + lk];
        float4 w1 = *(const float4*)&W[(size_t)(n0 + lr + 32) * D_ + k0 + lk];
        *(float4*)&Ws[lr][lk] = w0;
        *(float4*)&Ws[lr + 32][lk] = w1;
      }
      __syncthreads();
      #pragma unroll
      for (int kk = 0; kk < 32; kk += 4) {
        float4 av[4], wv[4];
        #pragma unroll
        for (int i = 0; i < 4; ++i) av[i] = *(const float4*)&As[ty * 4 + i][kk];
        #pragma unroll
        for (int j = 0; j < 4; ++j) wv[j] = *(const float4*)&Ws[tx + 16 * j][kk];
        #pragma unroll
        for (int i = 0; i < 4; ++i)
          #pragma unroll
          for (int j = 0; j < 4; ++j) {
            acc[i][j] = fma((double)av[i].x, (double)wv[j].x, acc[i][j]);
            acc[i][j] = fma((double)av[i].y, (double)wv[j].y, acc[i][j]);
            acc[i][j] = fma((double)av[i].z, (double)wv[j].z, acc[i][j]);
            acc[i][j] = fma((double)av[i].w, (double)wv[j].w, acc[i][j]);
          }
      }
    }
    #pragma unroll
    for (int i = 0; i < 4; ++i) {
      const int m = m0 + ty * 4 + i;
      #pragma unroll
      for (int j = 0; j < 4; ++j) {
        const int n = n0 + tx + 16 * j;
        const double v = acc[i][j] + (double)bias[n];
        qp64[(size_t)m * D_ + n] = v;
        qpb[(size_t)m * D_ + n] = __float2bfloat16((float)v);
      }
    }
    return;
  }

  // ---- cvt + norm (fragment-major candb layout) ----
  const float* src;
  int e4, log2rpb, row_base;
  if (blk < 256 + 4096) { src = ctx; e4 = (blk - 256) * 256 + tid; log2rpb = 12; row_base = 0; }
  else                  { src = mem; e4 = (blk - 4352) * 256 + tid; log2rpb = 6; row_base = C_; }
  const int row = e4 >> 6;
  const int b = row >> log2rpb;
  const int r = row & ((1 << log2rpb) - 1);
  const int k4 = e4 & 63;
  const float4 v = ((const float4*)src)[e4];
  const int R = row_base + r;
  const int g = R >> 4, l15 = R & 15;
  const int k = k4 * 4;
  const int s = k >> 5, lg = (k & 31) >> 3, ii = k & 7;
  unsigned short* d = candb + (size_t)b * (NC * D_) +
                      (size_t)g * 4096 + s * 512 + lg * 128 + l15 * 8 + ii;
  ushort4 o;
  __hip_bfloat16 h0 = __float2bfloat16(v.x); o.x = *(unsigned short*)&h0;
  __hip_bfloat16 h1 = __float2bfloat16(v.y); o.y = *(unsigned short*)&h1;
  __hip_bfloat16 h2 = __float2bfloat16(v.z); o.z = *(unsigned short*)&h2;
  __hip_bfloat16 h3 = __float2bfloat16(v.w); o.w = *(unsigned short*)&h3;
  *(ushort4*)d = o;
  float sacc = v.x * v.x + v.y * v.y + v.z * v.z + v.w * v.w;
  #pragma unroll
  for (int off = 32; off > 0; off >>= 1) sacc += __shfl_down(sacc, off);
  if ((tid & 63) == 0) cn[b * NC + row_base + r] = sacc;
}

// ---------------- pass 1: MFMA + branchless sort4 + order-statistic list merge ----------------
#define INSERT_CANDS(ACC, CBASE)                                              \
  {                                                                           \
    const float4 cn4 = *(const float4*)&cnb[(CBASE) + lg * 4];                \
    unsigned k0, k1, k2, k3;                                                  \
    {                                                                         \
      unsigned kk[4];                                                         \
      _Pragma("unroll")                                                       \
      for (int r = 0; r < 4; ++r) {                                           \
        const float d2v = fmaf(-2.0f, (ACC)[r], ((const float*)&cn4)[r]);     \
        kk[r] = (__float_as_uint(d2v) & 0xFFFFE000u)                          \
                | (unsigned)((CBASE) + lg * 4 + r);                           \
      }                                                                       \
      unsigned t;                                                             \
      t = UMIN(kk[0], kk[1]); kk[1] = UMAX(kk[0], kk[1]); kk[0] = t;          \
      t = UMIN(kk[2], kk[3]); kk[3] = UMAX(kk[2], kk[3]); kk[2] = t;          \
      t = UMIN(kk[0], kk[2]); kk[2] = UMAX(kk[0], kk[2]); kk[0] = t;          \
      t = UMIN(kk[1], kk[3]); kk[3] = UMAX(kk[1], kk[3]); kk[1] = t;          \
      t = UMIN(kk[1], kk[2]); kk[2] = UMAX(kk[1], kk[2]); kk[1] = t;          \
      k0 = kk[0]; k1 = kk[1]; k2 = kk[2]; k3 = kk[3];                         \
    }                                                                         \
    unsigned nl[16];                                                          \
    nl[0] = UMIN(ld[0], k0);                                                  \
    nl[1] = UMIN(UMIN(ld[1], UMAX(ld[0], k0)), k1);                           \
    nl[2] = UMIN(UMIN(ld[2], UMAX(ld[1], k0)),                                \
                 UMIN(UMAX(ld[0], k1), k2));                                  \
    nl[3] = UMIN(UMIN(UMIN(ld[3], UMAX(ld[2], k0)),                           \
                      UMIN(UMAX(ld[1], k1), UMAX(ld[0], k2))), k3);           \
    _Pragma("unroll")                                                         \
    for (int i = 4; i < 16; ++i) {                                            \
      nl[i] = UMIN(UMIN(UMIN(ld[i], UMAX(ld[i - 1], k0)),                     \
                        UMIN(UMAX(ld[i - 2], k1), UMAX(ld[i - 3], k2))),      \
                   UMAX(ld[i - 4], k3));                                      \
    }                                                                         \
    _Pragma("unroll")                                                         \
    for (int i = 0; i < 16; ++i) ld[i] = nl[i];                               \
  }

#define MFMA_CHAIN(ACC, FRAGS)                                                \
  f32x4 ACC;                                                                  \
  {                                                                           \
    f32x4 c0_ = {0.f,0.f,0.f,0.f}, c1_ = {0.f,0.f,0.f,0.f};                   \
    f32x4 c2_ = {0.f,0.f,0.f,0.f}, c3_ = {0.f,0.f,0.f,0.f};                   \
    c0_ = __builtin_amdgcn_mfma_f32_16x16x32_bf16((FRAGS)[0], bfr[0], c0_, 0, 0, 0); \
    c1_ = __builtin_amdgcn_mfma_f32_16x16x32_bf16((FRAGS)[1], bfr[1], c1_, 0, 0, 0); \
    c2_ = __builtin_amdgcn_mfma_f32_16x16x32_bf16((FRAGS)[2], bfr[2], c2_, 0, 0, 0); \
    c3_ = __builtin_amdgcn_mfma_f32_16x16x32_bf16((FRAGS)[3], bfr[3], c3_, 0, 0, 0); \
    c0_ = __builtin_amdgcn_mfma_f32_16x16x32_bf16((FRAGS)[4], bfr[4], c0_, 0, 0, 0); \
    c1_ = __builtin_amdgcn_mfma_f32_16x16x32_bf16((FRAGS)[5], bfr[5], c1_, 0, 0, 0); \
    c2_ = __builtin_amdgcn_mfma_f32_16x16x32_bf16((FRAGS)[6], bfr[6], c2_, 0, 0, 0); \
    c3_ = __builtin_amdgcn_mfma_f32_16x16x32_bf16((FRAGS)[7], bfr[7], c3_, 0, 0, 0); \
    ACC = (c0_ + c1_) + (c2_ + c3_);                                          \
  }

// grid 2048 = 4 batch x 8 split x 64 row-tiles. Per wave: 8 groups (4 j x 2).
__global__ __launch_bounds__(256) void dist_topk_kernel(
    const __hip_bfloat16* __restrict__ qpb, const unsigned short* __restrict__ candb,
    const float* __restrict__ cn, unsigned* __restrict__ topidx)
{
  const int b = blockIdx.x & 3;
  const int split = (blockIdx.x >> 2) & 7;
  const int rt = blockIdx.x >> 5;          // 0..63
  const int row0 = rt * 16;
  const int tid = threadIdx.x;
  const int w = tid >> 6;          // wave 0..3
  const int lane = tid & 63;
  const int l15 = lane & 15;
  const int lg = lane >> 4;        // 0..3

  __shared__ unsigned md[16][16][17];   // [row][list][entry], pad 17

  short8 bfr[8];
  {
    const short* qrow = (const short*)qpb + ((size_t)(b * S_ + row0 + l15)) * D_ + lg * 8;
    #pragma unroll
    for (int s = 0; s < 8; ++s) bfr[s] = *(const short8*)(qrow + s * 32);
  }

  const float* cnb = cn + b * NC;
  const short* cbp = (const short*)candb + (size_t)b * NC * D_ + lg * 128 + l15 * 8;

  unsigned ld[16];
  #pragma unroll
  for (int i = 0; i < TOPN; ++i) ld[i] = 0xFFFFFFFFu;

  const bool has_tail = (w == 3 && split < 4);
  const int gtail = 256 + split;

  short8 aA[8], aB[8];
  #pragma unroll
  for (int s = 0; s < 8; ++s)
    aA[s] = *(const short8*)(cbp + (size_t)(split + 8 * w) * 4096 + s * 512);

  for (int j = 0; j < 4; ++j) {
    const int gA = split + 8 * (w + 8 * j);
    const int gB = gA + 32;
    #pragma unroll
    for (int s = 0; s < 8; ++s)
      aB[s] = *(const short8*)(cbp + (size_t)gB * 4096 + s * 512);

    MFMA_CHAIN(acc, aA);

    if (j < 3) {
      #pragma unroll
      for (int s = 0; s < 8; ++s)
        aA[s] = *(const short8*)(cbp + (size_t)(gA + 64) * 4096 + s * 512);
    } else if (has_tail) {
      #pragma unroll
      for (int s = 0; s < 8; ++s)
        aA[s] = *(const short8*)(cbp + (size_t)gtail * 4096 + s * 512);
    }

    MFMA_CHAIN(acc2, aB);

    INSERT_CANDS(acc, gA * 16);
    INSERT_CANDS(acc2, gB * 16);
  }
  if (has_tail) {   // memory-candidate group
    MFMA_CHAIN(acc, aA);
    INSERT_CANDS(acc, gtail * 16);
  }

  const int lid = w * 4 + lg;
  #pragma unroll
  for (int i = 0; i < TOPN; ++i) md[l15][lid][i] = ld[i];
  __syncthreads();

  {
    const int g = lane >> 4;          // row-in-wave 0..3
    const int h = l15;                // list id
    const int row = w * 4 + g;
    int ptr = 0;
    unsigned cur = md[row][h][0];
    unsigned mykey = 0xFFFFFFFFu;     // lane h captures the h-th smallest
    #pragma unroll
    for (int it = 0; it < TOPN; ++it) {
      unsigned m = cur;
      #pragma unroll
      for (int off = 8; off > 0; off >>= 1) {
        const unsigned o = __shfl_xor(m, off, 16);
        m = (o < m) ? o : m;
      }
      if (h == it) mykey = m;
      if (cur == m) {                 // unique winner advances its head
        ++ptr;
        cur = (ptr < TOPN) ? md[row][h][ptr] : 0xFFFFFFFFu;
      }
    }
    unsigned* dst = topidx + ((size_t)(b * S_ + row0 + row)) * CANDK + split * TOPN;
    dst[h] = mykey;
  }
}

// ---------------- pass 2: dual key-presort -> select 32 -> fp64 refine -> bitonic top-16 ----------------
__global__ __launch_bounds__(256) void refine_kernel(
    const double* __restrict__ qp64, const float* __restrict__ ctx,
    const float* __restrict__ mem, const unsigned* __restrict__ topidx,
    float* __restrict__ out)
{
  const int row_global = blockIdx.x;
  const int tid = threadIdx.x;
  const int w = tid >> 6;         // wave 0..3: candidates [w*8, w*8+8)
  const int lane = tid & 63;
  const int c2 = lane >> 5;       // which cand of the pair
  const int ll = lane & 31;       // dim slice: [ll*8, ll*8+8)
  const int b = row_global >> 10;

  __shared__ unsigned sA[64], sB[64];
  __shared__ double d2s[64];
  __shared__ int    ids_s[64];

  // waves 0 and 1: bitonic-sort the two 64-key halves (ascending)
  if (w < 2) {
    unsigned key = topidx[(size_t)row_global * CANDK + w * 64 + lane];
    #pragma unroll
    for (int k = 2; k <= 64; k <<= 1) {
      #pragma unroll
      for (int j2 = k >> 1; j2 > 0; j2 >>= 1) {
        const unsigned o = __shfl_xor(key, j2);
        const bool up = ((lane & k) == 0);
        const bool keep_min = (((lane & j2) == 0) == up);
        const bool less = key < o;
        if (keep_min ? !less : less) key = o;
      }
    }
    if (w == 0) sA[lane] = key; else sB[lane] = key;
  }
  if (w == 2 && lane < 32) { d2s[32 + lane] = DBL_MAX; ids_s[32 + lane] = 0x7fffffff; }
  __syncthreads();

  const double* qrow = qp64 + (size_t)row_global * D_;
  double qd[8];
  #pragma unroll
  for (int t = 0; t < 8; t += 2) {
    double2 v = *(const double2*)&qrow[ll * 8 + t];
    qd[t] = v.x; qd[t + 1] = v.y;
  }

  // smallest-32 of two sorted-64s: sel(p) = min(sA[p], sB[31-p]), p = 0..31
  int cis[4]; float4 cva[4], cvb[4];
  #pragma unroll
  for (int j = 0; j < 4; ++j) {
    const int p = w * 8 + 2 * j + c2;
    const unsigned kk = UMIN(sA[p], sB[31 - p]);
    cis[j] = (int)(kk & 0x1FFFu);
  }
  #pragma unroll
  for (int j = 0; j < 4; ++j) {
    const int ci = cis[j];
    const float* cp = (ci < C_) ? ctx + ((size_t)b * C_ + ci) * D_
                                : mem + ((size_t)b * K_ + (ci - C_)) * D_;
    cva[j] = *(const float4*)&cp[ll * 8];
    cvb[j] = *(const float4*)&cp[ll * 8 + 4];
  }

  #pragma unroll
  for (int j = 0; j < 4; ++j) {
    double a0 = 0.0, a1 = 0.0, df;
    df = qd[0] - (double)cva[j].x; a0 = fma(df, df, a0);
    df = qd[1] - (double)cva[j].y; a1 = fma(df, df, a1);
    df = qd[2] - (double)cva[j].z; a0 = fma(df, df, a0);
    df = qd[3] - (double)cva[j].w; a1 = fma(df, df, a1);
    df = qd[4] - (double)cvb[j].x; a0 = fma(df, df, a0);
    df = qd[5] - (double)cvb[j].y; a1 = fma(df, df, a1);
    df = qd[6] - (double)cvb[j].z; a0 = fma(df, df, a0);
    df = qd[7] - (double)cvb[j].w; a1 = fma(df, df, a1);
    double acc = a0 + a1;
    #pragma unroll
    for (int off = 16; off > 0; off >>= 1) acc += __shfl_down(acc, off, 32);
    if (ll == 0) { d2s[w * 8 + 2 * j + c2] = acc; ids_s[w * 8 + 2 * j + c2] = cis[j]; }
  }
  __syncthreads();

  // wave 0: exact bitonic sort of 32 real + 32 pad (d2, idx) pairs
  if (w == 0) {
    double d2 = d2s[lane];
    int    ci = ids_s[lane];
    #pragma unroll
    for (int k = 2; k <= 64; k <<= 1) {
      #pragma unroll
      for (int j2 = k >> 1; j2 > 0; j2 >>= 1) {
        const double od2 = __shfl_xor(d2, j2);
        const int    oci = __shfl_xor(ci, j2);
        const bool up = ((lane & k) == 0);
        const bool less = (d2 < od2) || (d2 == od2 && ci < oci);
        const bool keep_min = (((lane & j2) == 0) == up);
        const bool take = keep_min ? !less : less;
        if (take) { d2 = od2; ci = oci; }
      }
    }
    if (lane < TOPN) {
      const size_t obase = (size_t)row_global * TOPN;
      out[obase + lane] = (float)sqrt(d2 < 0.0 ? 0.0 : d2);
      out[(size_t)B_ * S_ * TOPN + obase + lane] = (float)ci;
    }
  }
}

extern "C" void kernel_launch(void* const* d_in, const int* in_sizes, int n_in,
                              void* d_out, int out_size, void* d_ws, size_t ws_size,
                              hipStream_t stream) {
  const float* q    = (const float*)d_in[0];
  const float* ctx  = (const float*)d_in[1];
  const float* mem  = (const float*)d_in[2];
  const float* W    = (const float*)d_in[3];
  const float* bias = (const float*)d_in[4];
  float* out = (float*)d_out;

  double* qp64 = (double*)d_ws;                                             // 8 MB
  __hip_bfloat16* qpb = (__hip_bfloat16*)(qp64 + (size_t)B_ * S_ * D_);     // 2 MB
  unsigned short* candb = (unsigned short*)(qpb + (size_t)B_ * S_ * D_);    // 8.5 MB
  float* cn    = (float*)(candb + (size_t)B_ * NC * D_);                    // 66.5 KB
  unsigned* topidx = (unsigned*)(cn + (size_t)B_ * NC);                     // 2 MB

  prep_kernel<<<4416, 256, 0, stream>>>(q, W, bias, qp64, qpb, ctx, mem, candb, cn);
  dist_topk_kernel<<<2048, 256, 0, stream>>>(qpb, candb, cn, topidx);
  refine_kernel<<<B_ * S_, 256, 0, stream>>>(qp64, ctx, mem, topidx, out);
}